// Round 2
// baseline (3027.268 us; speedup 1.0000x reference)
//
#include <hip/hip_runtime.h>
#include <cstdint>
#include <cstddef>

// Problem constants (SuperGraphConstruction)
#define NN 100000      // nodes
#define NC 20000       // clusters
#define LATD 128
#define HIDD 512
#define EMBD 12
#define NES 160000     // super edges
#define NEB 800000     // bipartite edges

enum { ACT_NONE = 0, ACT_TANH = 1, ACT_RELU = 2 };

__device__ __forceinline__ float fast_tanh(float x) {
    return 1.f - 2.f / (__expf(2.f * x) + 1.f);
}

// ---------------------------------------------------------------------------
// Generic tiled fp32 GEMM: C[M,N] = act(A[M,K] @ B[K,N] + bias)
// GATHER mode: A row m is concat(gsrc[g0[m]][0:128], gsrc[g1[m]][0:128]), K=256
// BM=BN=64, BK=16, 256 threads, 4x4 per thread.
// ---------------------------------------------------------------------------
template<int ACT, bool GATHER>
__global__ __launch_bounds__(256) void gemm_tiled(
    const float* __restrict__ A, const float* __restrict__ B,
    const float* __restrict__ bias, float* __restrict__ C,
    int M, int N, int K,
    const int* __restrict__ g0, const int* __restrict__ g1,
    const float* __restrict__ gsrc)
{
    __shared__ float As[16][68];   // [k][m], padded
    __shared__ float Bs[16][68];   // [k][n], padded
    const int tid = threadIdx.x;
    const int m0 = blockIdx.y * 64, n0 = blockIdx.x * 64;
    const int tx = tid & 15, ty = tid >> 4;
    const int a_k = tid & 15, a_m = tid >> 4;  // A tile: row a_m+16p, col a_k
    const int b_n = tid & 63, b_k = tid >> 6;  // B tile: row b_k+4p, col b_n

    int gr0[4], gr1[4];
    if (GATHER) {
#pragma unroll
        for (int p = 0; p < 4; ++p) {
            int gm = m0 + a_m + 16 * p;
            gr0[p] = (gm < M) ? g0[gm] : 0;
            gr1[p] = (gm < M) ? g1[gm] : 0;
        }
    }

    float acc[4][4] = {};
    for (int k0 = 0; k0 < K; k0 += 16) {
#pragma unroll
        for (int p = 0; p < 4; ++p) {
            int mm = a_m + 16 * p;
            int gm = m0 + mm;
            int kk = k0 + a_k;
            float v = 0.f;
            if (!GATHER) {
                if (gm < M) v = A[(size_t)gm * K + kk];
            } else {
                if (gm < M) {
                    int row = (kk < LATD) ? gr0[p] : gr1[p];
                    v = gsrc[(size_t)row * LATD + (kk & (LATD - 1))];
                }
            }
            As[a_k][mm] = v;
        }
#pragma unroll
        for (int p = 0; p < 4; ++p) {
            int kk = b_k + 4 * p;
            Bs[kk][b_n] = B[(size_t)(k0 + kk) * N + (n0 + b_n)];
        }
        __syncthreads();
#pragma unroll
        for (int k = 0; k < 16; ++k) {
            float av[4], bv[4];
#pragma unroll
            for (int i = 0; i < 4; ++i) av[i] = As[k][ty * 4 + i];
#pragma unroll
            for (int j = 0; j < 4; ++j) bv[j] = Bs[k][tx * 4 + j];
#pragma unroll
            for (int i = 0; i < 4; ++i)
#pragma unroll
                for (int j = 0; j < 4; ++j)
                    acc[i][j] += av[i] * bv[j];
        }
        __syncthreads();
    }

#pragma unroll
    for (int i = 0; i < 4; ++i) {
        int gm = m0 + ty * 4 + i;
        if (gm >= M) continue;
#pragma unroll
        for (int j = 0; j < 4; ++j) {
            int gn = n0 + tx * 4 + j;
            float v = acc[i][j] + bias[gn];
            if (ACT == ACT_TANH) v = fast_tanh(v);
            else if (ACT == ACT_RELU) v = fmaxf(v, 0.f);
            C[(size_t)gm * N + gn] = v;
        }
    }
}

// ---------------------------------------------------------------------------
// embeddings = l2norm(h2 @ Wc3 + bc3); wave-per-row, Wc3 staged transposed.
// ---------------------------------------------------------------------------
__global__ __launch_bounds__(256) void emb_kernel(
    const float* __restrict__ h2, const float* __restrict__ W,  // [512][12]
    const float* __restrict__ bias, float* __restrict__ out, int M)
{
    __shared__ float Wl[EMBD][HIDD];  // transposed: Wl[j][k]
    for (int i = threadIdx.x; i < HIDD * EMBD; i += 256) {
        int k = i / EMBD, j = i % EMBD;
        Wl[j][k] = W[i];
    }
    __syncthreads();
    const int wave = threadIdx.x >> 6;
    const int lane = threadIdx.x & 63;
    const int m = blockIdx.x * 4 + wave;
    if (m >= M) return;

    float acc[EMBD] = {};
    const float* row = h2 + (size_t)m * HIDD;
#pragma unroll
    for (int c = 0; c < HIDD / 64; ++c) {
        float hv = row[c * 64 + lane];
#pragma unroll
        for (int j = 0; j < EMBD; ++j)
            acc[j] += hv * Wl[j][c * 64 + lane];
    }
#pragma unroll
    for (int j = 0; j < EMBD; ++j) {
        float v = acc[j];
#pragma unroll
        for (int s = 32; s >= 1; s >>= 1) v += __shfl_xor(v, s, 64);
        acc[j] = v + bias[j];
    }
    float ss = 0.f;
#pragma unroll
    for (int j = 0; j < EMBD; ++j) ss += acc[j] * acc[j];
    float inv = 1.f / fmaxf(sqrtf(ss), 1e-12f);
    if (lane < EMBD) out[(size_t)m * EMBD + lane] = acc[lane] * inv;
}

// ---------------------------------------------------------------------------
// cluster sums + counts (atomics; only 1.3M adds)
// ---------------------------------------------------------------------------
__global__ void cluster_accum(const float* __restrict__ emb,
                              const int* __restrict__ clusters,
                              float* __restrict__ csums, float* __restrict__ ccnt)
{
    int i = blockIdx.x * 256 + threadIdx.x;
    if (i >= NN * EMBD) return;
    int n = i / EMBD, j = i % EMBD;
    int c = clusters[n];
    atomicAdd(&csums[(size_t)c * EMBD + j], emb[i]);
    if (j == 0) atomicAdd(&ccnt[c], 1.f);
}

__global__ void means_kernel(const float* __restrict__ csums,
                             const float* __restrict__ ccnt,
                             float* __restrict__ means)
{
    int c = blockIdx.x * 256 + threadIdx.x;
    if (c >= NC) return;
    float cv = fmaxf(ccnt[c], 1.f);
    float v[EMBD];
    float ss = 0.f;
#pragma unroll
    for (int j = 0; j < EMBD; ++j) {
        v[j] = csums[(size_t)c * EMBD + j] / cv;
        ss += v[j] * v[j];
    }
    float inv = 1.f / fmaxf(sqrtf(ss), 1e-12f);
#pragma unroll
    for (int j = 0; j < EMBD; ++j) means[(size_t)c * EMBD + j] = v[j] * inv;
}

// ---------------------------------------------------------------------------
// block-reduced sum/sumsq -> atomics
// ---------------------------------------------------------------------------
__device__ __forceinline__ void block_stats(float x, float* s_sum, float* s_sumsq)
{
    float x2 = x * x;
#pragma unroll
    for (int s = 32; s >= 1; s >>= 1) {
        x += __shfl_xor(x, s, 64);
        x2 += __shfl_xor(x2, s, 64);
    }
    __shared__ float w0[4], w1[4];
    int lane = threadIdx.x & 63, w = threadIdx.x >> 6;
    if (lane == 0) { w0[w] = x; w1[w] = x2; }
    __syncthreads();
    if (threadIdx.x == 0) {
        float a = 0.f, b = 0.f;
        for (int i = 0; i < 4; ++i) { a += w0[i]; b += w1[i]; }
        atomicAdd(s_sum, a);
        atomicAdd(s_sumsq, b);
    }
}

__global__ __launch_bounds__(256) void sg_lik_kernel(
    const float* __restrict__ means, const int* __restrict__ sg0,
    const int* __restrict__ sg1, float* __restrict__ sg_lik, float* __restrict__ stats)
{
    int e = blockIdx.x * 256 + threadIdx.x;
    float x = 0.f;
    if (e < NES) {
        const float* a = means + (size_t)sg0[e] * EMBD;
        const float* b = means + (size_t)sg1[e] * EMBD;
        float s = 0.f;
#pragma unroll
        for (int j = 0; j < EMBD; ++j) s += a[j] * b[j];
        sg_lik[e] = s;
        x = s;
    }
    block_stats(x, &stats[0], &stats[1]);
}

__global__ __launch_bounds__(256) void sgw_kernel(
    const float* __restrict__ sg_lik, const float* __restrict__ stats,
    const float* __restrict__ gamma, const float* __restrict__ beta,
    float* __restrict__ out)
{
    int e = blockIdx.x * 256 + threadIdx.x;
    if (e >= NES) return;
    float m = stats[0] / (float)NES;
    float var = stats[1] / (float)NES - m * m;
    float y = (sg_lik[e] - m) * rsqrtf(var + 1e-5f) * gamma[0] + beta[0];
    out[e] = 1.f / (1.f + __expf(-y));
}

__global__ __launch_bounds__(256) void bg_lik_kernel(
    const float* __restrict__ emb, const float* __restrict__ means,
    const int* __restrict__ bg_src, const int* __restrict__ bg_dst,
    float* __restrict__ bg_lik, float* __restrict__ stats)
{
    int e = blockIdx.x * 256 + threadIdx.x;
    float x = 0.f;
    if (e < NEB) {
        const float* a = emb + (size_t)bg_src[e] * EMBD;
        const float* b = means + (size_t)bg_dst[e] * EMBD;
        float s = 0.f;
#pragma unroll
        for (int j = 0; j < EMBD; ++j) s += a[j] * b[j];
        bg_lik[e] = s;
        x = s;
    }
    block_stats(x, &stats[2], &stats[3]);
}

__global__ __launch_bounds__(256) void bw_kernel(
    const float* __restrict__ bg_lik, const float* __restrict__ stats,
    const float* __restrict__ gamma, const float* __restrict__ beta,
    const int* __restrict__ bg_src, float* __restrict__ bw, float* __restrict__ denom)
{
    int e = blockIdx.x * 256 + threadIdx.x;
    if (e >= NEB) return;
    float m = stats[2] / (float)NEB;
    float var = stats[3] / (float)NEB - m * m;
    float y = (bg_lik[e] - m) * rsqrtf(var + 1e-5f) * gamma[0] + beta[0];
    float w = __expf(y);
    bw[e] = w;
    atomicAdd(&denom[bg_src[e]], w);
}

__global__ __launch_bounds__(256) void bw_norm_kernel(
    float* __restrict__ bw, const float* __restrict__ denom,
    const int* __restrict__ bg_src, float* __restrict__ out)
{
    int e = blockIdx.x * 256 + threadIdx.x;
    if (e >= NEB) return;
    float w = bw[e] / (1e-12f + denom[bg_src[e]]);
    bw[e] = w;
    out[e] = w;
}

// ---------------------------------------------------------------------------
// counting sort of bipartite edges by bg_dst
// ---------------------------------------------------------------------------
__global__ void hist_kernel(const int* __restrict__ bg_dst, int* __restrict__ cnt)
{
    int e = blockIdx.x * 256 + threadIdx.x;
    if (e >= NEB) return;
    atomicAdd(&cnt[bg_dst[e]], 1);
}

__global__ __launch_bounds__(1024) void scan_kernel(
    const int* __restrict__ cnt, int* __restrict__ offs, int C)
{
    __shared__ int wsum[16];
    __shared__ int carry_s, ctot_s;
    const int tid = threadIdx.x;
    const int lane = tid & 63, w = tid >> 6;
    if (tid == 0) carry_s = 0;
    __syncthreads();
    for (int base = 0; base < C; base += 1024) {
        int i = base + tid;
        int v = (i < C) ? cnt[i] : 0;
        int x = v;
#pragma unroll
        for (int s = 1; s < 64; s <<= 1) {
            int y = __shfl_up(x, s, 64);
            if (lane >= s) x += y;
        }
        if (lane == 63) wsum[w] = x;
        __syncthreads();
        if (tid == 0) {
            int s = 0;
            for (int k = 0; k < 16; ++k) { int t = wsum[k]; wsum[k] = s; s += t; }
            ctot_s = s;
        }
        __syncthreads();
        int excl = carry_s + wsum[w] + (x - v);
        if (i < C) offs[i] = excl;
        __syncthreads();
        if (tid == 0) carry_s += ctot_s;
        __syncthreads();
    }
    if (tid == 0) offs[C] = carry_s;
}

__global__ void scatter_kernel(const int* __restrict__ bg_dst,
                               const int* __restrict__ offs,
                               int* __restrict__ fill, int* __restrict__ eids)
{
    int e = blockIdx.x * 256 + threadIdx.x;
    if (e >= NEB) return;
    int d = bg_dst[e];
    int p = atomicAdd(&fill[d], 1);
    eids[offs[d] + p] = e;
}

// ---------------------------------------------------------------------------
// supernodes[c][:] = sum_{e: bg_dst[e]==c} bw[e]*node_messages[bg_src[e]][:]
// one block (128 threads) per cluster, register accumulation, no atomics.
// ---------------------------------------------------------------------------
__global__ __launch_bounds__(128) void supernodes_kernel(
    const float* __restrict__ nmsg, const float* __restrict__ bw,
    const int* __restrict__ bg_src, const int* __restrict__ eids,
    const int* __restrict__ offs, float* __restrict__ sn)
{
    int c = blockIdx.x;
    int t = threadIdx.x;
    int beg = offs[c], end = offs[c + 1];
    float acc = 0.f;
    for (int p = beg; p < end; ++p) {
        int e = eids[p];
        int s = bg_src[e];
        float w = bw[e];
        acc += w * nmsg[(size_t)s * LATD + t];
    }
    sn[(size_t)c * LATD + t] = acc;
}

// ---------------------------------------------------------------------------
extern "C" void kernel_launch(void* const* d_in, const int* in_sizes, int n_in,
                              void* d_out, int out_size, void* d_ws, size_t ws_size,
                              hipStream_t stream)
{
    const float* emb_nodes = (const float*)d_in[0];
    const float* enc_nodes = (const float*)d_in[1];
    const float* Wc1 = (const float*)d_in[2];  const float* bc1 = (const float*)d_in[3];
    const float* Wc2 = (const float*)d_in[4];  const float* bc2 = (const float*)d_in[5];
    const float* Wc3 = (const float*)d_in[6];  const float* bc3 = (const float*)d_in[7];
    const float* Wn1 = (const float*)d_in[8];  const float* cn1 = (const float*)d_in[9];
    const float* Wn2 = (const float*)d_in[10]; const float* cn2 = (const float*)d_in[11];
    const float* We1 = (const float*)d_in[12]; const float* ce1 = (const float*)d_in[13];
    const float* We2 = (const float*)d_in[14]; const float* ce2 = (const float*)d_in[15];
    const float* sg_gamma = (const float*)d_in[16]; const float* sg_beta = (const float*)d_in[17];
    const float* bg_gamma = (const float*)d_in[18]; const float* bg_beta = (const float*)d_in[19];
    const int* clusters = (const int*)d_in[20];
    const int* sg0 = (const int*)d_in[21];
    const int* sg1 = sg0 + NES;
    const int* bg_src = (const int*)d_in[22];
    const int* bg_dst = (const int*)d_in[23];

    // output layout (flat, return order)
    float* out_emb = (float*)d_out;                       // NN*EMBD
    float* out_sn  = out_emb + (size_t)NN * EMBD;         // NC*LATD
    float* out_se  = out_sn + (size_t)NC * LATD;          // NES*LATD
    float* out_bw  = out_se + (size_t)NES * LATD;         // NEB
    float* out_sew = out_bw + (size_t)NEB;                // NES

    // ---------------- workspace layout (sized from ws_size) ----------------
    float* wsf = (float*)d_ws;
    size_t ws_floats = ws_size / 4;

    float* nmsg  = wsf;                         // NN*LATD = 12.8M floats
    float* zbase = nmsg + (size_t)NN * LATD;    // zeroed region start
    float* csums = zbase;                       // NC*EMBD = 240000
    float* ccnt  = csums + (size_t)NC * EMBD;   // 20000
    float* denom = ccnt + NC;                   // 100000
    float* stats = denom + NN;                  // 8
    int*   cnt   = (int*)(stats + 8);           // NC
    int*   fill  = cnt + NC;                    // NC
    size_t zero_bytes = ((size_t)NC * EMBD + NC + NN + 8 + NC + NC) * 4;

    float* means  = (float*)(fill + NC);        // NC*EMBD
    float* sg_lik = means + (size_t)NC * EMBD;  // NES
    float* bg_lik = sg_lik + NES;               // NEB
    float* bwv    = bg_lik + NEB;               // NEB
    int*   offs   = (int*)(bwv + NEB);          // NC+1
    int*   eids   = offs + (NC + 1);            // NEB
    float* bufs   = (float*)(eids + NEB);       // chunk ping-pong buffers

    size_t fixed_floats = (size_t)(bufs - wsf);
    if (ws_floats < fixed_floats + 2 * 64 * HIDD) return;  // can't run: fail soft
    size_t avail = ws_floats - fixed_floats;
    size_t chunk_sz = (avail / (2 * (size_t)HIDD)) & ~(size_t)63;
    if (chunk_sz > 51200) chunk_sz = 51200;
    const int CH = (int)chunk_sz;
    float* bufA = bufs;
    float* bufB = bufs + (size_t)CH * HIDD;

    hipMemsetAsync(zbase, 0, zero_bytes, stream);

    dim3 blk(256);

    // ---- fused node chain, chunked: emb->h1->h2->embeddings ----
    for (int m0 = 0; m0 < NN; m0 += CH) {
        int cm = (NN - m0 < CH) ? (NN - m0) : CH;
        gemm_tiled<ACT_TANH, false><<<dim3(HIDD / 64, (cm + 63) / 64), blk, 0, stream>>>(
            emb_nodes + (size_t)m0 * LATD, Wc1, bc1, bufA, cm, HIDD, LATD,
            nullptr, nullptr, nullptr);
        gemm_tiled<ACT_TANH, false><<<dim3(HIDD / 64, (cm + 63) / 64), blk, 0, stream>>>(
            bufA, Wc2, bc2, bufB, cm, HIDD, HIDD, nullptr, nullptr, nullptr);
        emb_kernel<<<(cm + 3) / 4, blk, 0, stream>>>(
            bufB, Wc3, bc3, out_emb + (size_t)m0 * EMBD, cm);
    }

    // ---- cluster means ----
    cluster_accum<<<(NN * EMBD + 255) / 256, blk, 0, stream>>>(out_emb, clusters, csums, ccnt);
    means_kernel<<<(NC + 255) / 256, blk, 0, stream>>>(csums, ccnt, means);

    // ---- super edge weights ----
    sg_lik_kernel<<<(NES + 255) / 256, blk, 0, stream>>>(means, sg0, sg1, sg_lik, stats);
    sgw_kernel<<<(NES + 255) / 256, blk, 0, stream>>>(sg_lik, stats, sg_gamma, sg_beta, out_sew);

    // ---- bipartite edge weights ----
    bg_lik_kernel<<<(NEB + 255) / 256, blk, 0, stream>>>(out_emb, means, bg_src, bg_dst, bg_lik, stats);
    bw_kernel<<<(NEB + 255) / 256, blk, 0, stream>>>(bg_lik, stats, bg_gamma, bg_beta, bg_src, bwv, denom);
    bw_norm_kernel<<<(NEB + 255) / 256, blk, 0, stream>>>(bwv, denom, bg_src, out_bw);

    // ---- counting sort of edges by destination cluster ----
    hist_kernel<<<(NEB + 255) / 256, blk, 0, stream>>>(bg_dst, cnt);
    scan_kernel<<<1, 1024, 0, stream>>>(cnt, offs, NC);
    scatter_kernel<<<(NEB + 255) / 256, blk, 0, stream>>>(bg_dst, offs, fill, eids);

    // ---- node messages, chunked: enc->nm->nmsg(full) ----
    for (int m0 = 0; m0 < NN; m0 += CH) {
        int cm = (NN - m0 < CH) ? (NN - m0) : CH;
        gemm_tiled<ACT_RELU, false><<<dim3(HIDD / 64, (cm + 63) / 64), blk, 0, stream>>>(
            enc_nodes + (size_t)m0 * LATD, Wn1, cn1, bufA, cm, HIDD, LATD,
            nullptr, nullptr, nullptr);
        gemm_tiled<ACT_RELU, false><<<dim3(LATD / 64, (cm + 63) / 64), blk, 0, stream>>>(
            bufA, Wn2, cn2, nmsg + (size_t)m0 * LATD, cm, LATD, HIDD,
            nullptr, nullptr, nullptr);
    }

    // ---- supernodes (sorted edge lists, no atomics) ----
    supernodes_kernel<<<NC, 128, 0, stream>>>(nmsg, bwv, bg_src, eids, offs, out_sn);

    // ---- superedges, chunked (uses both buffers as one region: 2*CH rows) ----
    const int CE = 2 * CH;
    for (int e0 = 0; e0 < NES; e0 += CE) {
        int ce = (NES - e0 < CE) ? (NES - e0) : CE;
        gemm_tiled<ACT_RELU, true><<<dim3(HIDD / 64, (ce + 63) / 64), blk, 0, stream>>>(
            nullptr, We1, ce1, bufA, ce, HIDD, 2 * LATD, sg0 + e0, sg1 + e0, out_sn);
        gemm_tiled<ACT_RELU, false><<<dim3(LATD / 64, (ce + 63) / 64), blk, 0, stream>>>(
            bufA, We2, ce2, out_se + (size_t)e0 * LATD, ce, LATD, HIDD,
            nullptr, nullptr, nullptr);
    }
}

// Round 3
// 1366.246 us; speedup vs baseline: 2.2158x; 2.2158x over previous
//
#include <hip/hip_runtime.h>
#include <cstdint>
#include <cstddef>

// Problem constants (SuperGraphConstruction)
#define NN 100000      // nodes
#define NC 20000       // clusters
#define LATD 128
#define HIDD 512
#define EMBD 12
#define NES 160000     // super edges
#define NEB 800000     // bipartite edges

enum { ACT_NONE = 0, ACT_TANH = 1, ACT_RELU = 2 };

typedef __attribute__((ext_vector_type(8))) short bf16x8;
typedef __attribute__((ext_vector_type(4))) float f32x4;
typedef unsigned short ushort_t;

__device__ __forceinline__ float fast_tanh(float x) {
    return 1.f - 2.f / (__expf(2.f * x) + 1.f);
}
__device__ __forceinline__ ushort_t f2bf(float f) {
    union { float f; unsigned u; } x; x.f = f;
    unsigned r = x.u + 0x7FFFu + ((x.u >> 16) & 1u);  // RNE
    return (ushort_t)(r >> 16);
}
__device__ __forceinline__ float bf2f(ushort_t h) {
    union { unsigned u; float f; } x; x.u = ((unsigned)h) << 16;
    return x.f;
}

// ---------------------------------------------------------------------------
// fp32 -> bf16 elementwise (n multiple of 8 assumed at call sites)
// ---------------------------------------------------------------------------
__global__ __launch_bounds__(256) void conv_f2b_kernel(
    const float* __restrict__ in, ushort_t* __restrict__ out, long n)
{
    long i = ((long)blockIdx.x * 256 + threadIdx.x) * 8;
    long stride = (long)gridDim.x * 256 * 8;
    for (; i + 7 < n; i += stride) {
        float4 a = *(const float4*)(in + i);
        float4 b = *(const float4*)(in + i + 4);
        ushort_t o[8] = { f2bf(a.x), f2bf(a.y), f2bf(a.z), f2bf(a.w),
                          f2bf(b.x), f2bf(b.y), f2bf(b.z), f2bf(b.w) };
        *(int4*)(out + i) = *(int4*)o;
    }
}

// W [K][N] fp32 -> Wt [N][K] bf16  (small, launched per weight)
__global__ __launch_bounds__(256) void transpose_conv_kernel(
    const float* __restrict__ W, ushort_t* __restrict__ Wt, int K, int N)
{
    int i = blockIdx.x * 256 + threadIdx.x;
    if (i >= K * N) return;
    int n = i / K, k = i % K;
    Wt[i] = f2bf(W[(size_t)k * N + n]);
}

// ---------------------------------------------------------------------------
// bf16 MFMA GEMM: C[M,N] = act(A[M,K] @ B[K,N] + bias)
//   A bf16 row-major [M][K]; Bt bf16 PRE-TRANSPOSED [N][K]; bias fp32.
//   GATHER: A row m = concat(gsrc[g0[m]][0:128], gsrc[g1[m]][0:128]), K=256.
//   BM=BN=128, BK=64; 256 threads = 4 waves (2x2); each wave 64x64 out.
//   mfma_f32_16x16x32_bf16; N must be a multiple of 128, K of 64.
// ---------------------------------------------------------------------------
template<int ACT, bool GATHER, bool OUT_BF16>
__global__ __launch_bounds__(256) void gemm_mfma(
    const ushort_t* __restrict__ A, const ushort_t* __restrict__ Bt,
    const float* __restrict__ bias, void* __restrict__ Cv,
    int M, int N, int K,
    const int* __restrict__ g0, const int* __restrict__ g1,
    const ushort_t* __restrict__ gsrc)
{
    __shared__ ushort_t As[128][72];   // +8 pad: row stride 144B -> 2-way max
    __shared__ ushort_t Bs[128][72];

    const int tid = threadIdx.x;
    const int m0 = blockIdx.y * 128, n0 = blockIdx.x * 128;
    const int r0 = tid >> 3;          // 0..31 (staging row base)
    const int part = tid & 7;         // 0..7  (16B segment in row)
    const int w = tid >> 6, lane = tid & 63;
    const int wm = w >> 1, wn = w & 1;
    const int lr = lane & 15, lg = lane >> 4;

    int gr0[4], gr1[4];
    if (GATHER) {
#pragma unroll
        for (int p = 0; p < 4; ++p) {
            int gm = m0 + r0 + 32 * p;
            gr0[p] = (gm < M) ? g0[gm] : 0;
            gr1[p] = (gm < M) ? g1[gm] : 0;
        }
    }

    f32x4 acc[4][4];
#pragma unroll
    for (int i = 0; i < 4; ++i)
#pragma unroll
        for (int j = 0; j < 4; ++j) acc[i][j] = (f32x4){0.f, 0.f, 0.f, 0.f};

    for (int k0 = 0; k0 < K; k0 += 64) {
        // ---- stage A and B tiles (16B per thread per row-pass) ----
#pragma unroll
        for (int p = 0; p < 4; ++p) {
            int row = r0 + 32 * p;
            int4 va = {0, 0, 0, 0};
            int gm = m0 + row;
            if (!GATHER) {
                if (gm < M) va = *(const int4*)(A + (size_t)gm * K + k0 + part * 8);
            } else {
                if (gm < M) {
                    int kk = k0 + part * 8;
                    int src = (kk < LATD) ? gr0[p] : gr1[p];
                    va = *(const int4*)(gsrc + (size_t)src * LATD + (kk & (LATD - 1)));
                }
            }
            *(int4*)&As[row][part * 8] = va;
            int4 vb = *(const int4*)(Bt + (size_t)(n0 + row) * K + k0 + part * 8);
            *(int4*)&Bs[row][part * 8] = vb;
        }
        __syncthreads();

        // ---- 2 k-steps of 32 ----
#pragma unroll
        for (int ks = 0; ks < 2; ++ks) {
            bf16x8 af[4], bf[4];
#pragma unroll
            for (int mt = 0; mt < 4; ++mt)
                af[mt] = *(const bf16x8*)&As[wm * 64 + mt * 16 + lr][ks * 32 + lg * 8];
#pragma unroll
            for (int nt = 0; nt < 4; ++nt)
                bf[nt] = *(const bf16x8*)&Bs[wn * 64 + nt * 16 + lr][ks * 32 + lg * 8];
#pragma unroll
            for (int mt = 0; mt < 4; ++mt)
#pragma unroll
                for (int nt = 0; nt < 4; ++nt)
                    acc[mt][nt] = __builtin_amdgcn_mfma_f32_16x16x32_bf16(
                        af[mt], bf[nt], acc[mt][nt], 0, 0, 0);
        }
        __syncthreads();
    }

    // ---- epilogue: D lane,reg -> row=(lane>>4)*4+reg, col=lane&15 ----
#pragma unroll
    for (int nt = 0; nt < 4; ++nt) {
        int col = n0 + wn * 64 + nt * 16 + lr;
        float bv = bias[col];
#pragma unroll
        for (int mt = 0; mt < 4; ++mt) {
#pragma unroll
            for (int r = 0; r < 4; ++r) {
                int row = m0 + wm * 64 + mt * 16 + lg * 4 + r;
                if (row >= M) continue;
                float v = acc[mt][nt][r] + bv;
                if (ACT == ACT_TANH) v = fast_tanh(v);
                else if (ACT == ACT_RELU) v = fmaxf(v, 0.f);
                if (OUT_BF16) ((ushort_t*)Cv)[(size_t)row * N + col] = f2bf(v);
                else ((float*)Cv)[(size_t)row * N + col] = v;
            }
        }
    }
}

// ---------------------------------------------------------------------------
// embeddings = l2norm(h2 @ Wc3 + bc3); wave-per-row; h2 is bf16.
// ---------------------------------------------------------------------------
__global__ __launch_bounds__(256) void emb_kernel(
    const ushort_t* __restrict__ h2, const float* __restrict__ W,  // [512][12]
    const float* __restrict__ bias, float* __restrict__ out, int M)
{
    __shared__ float Wl[EMBD][HIDD];  // transposed: Wl[j][k]
    for (int i = threadIdx.x; i < HIDD * EMBD; i += 256) {
        int k = i / EMBD, j = i % EMBD;
        Wl[j][k] = W[i];
    }
    __syncthreads();
    const int wave = threadIdx.x >> 6;
    const int lane = threadIdx.x & 63;
    const int m = blockIdx.x * 4 + wave;
    if (m >= M) return;

    float acc[EMBD] = {};
    const ushort_t* row = h2 + (size_t)m * HIDD;
#pragma unroll
    for (int c = 0; c < HIDD / 64; ++c) {
        float hv = bf2f(row[c * 64 + lane]);
#pragma unroll
        for (int j = 0; j < EMBD; ++j)
            acc[j] += hv * Wl[j][c * 64 + lane];
    }
#pragma unroll
    for (int j = 0; j < EMBD; ++j) {
        float v = acc[j];
#pragma unroll
        for (int s = 32; s >= 1; s >>= 1) v += __shfl_xor(v, s, 64);
        acc[j] = v + bias[j];
    }
    float ss = 0.f;
#pragma unroll
    for (int j = 0; j < EMBD; ++j) ss += acc[j] * acc[j];
    float inv = 1.f / fmaxf(sqrtf(ss), 1e-12f);
    if (lane < EMBD) out[(size_t)m * EMBD + lane] = acc[lane] * inv;
}

// ---------------------------------------------------------------------------
__global__ void cluster_accum(const float* __restrict__ emb,
                              const int* __restrict__ clusters,
                              float* __restrict__ csums, float* __restrict__ ccnt)
{
    int i = blockIdx.x * 256 + threadIdx.x;
    if (i >= NN * EMBD) return;
    int n = i / EMBD, j = i % EMBD;
    int c = clusters[n];
    atomicAdd(&csums[(size_t)c * EMBD + j], emb[i]);
    if (j == 0) atomicAdd(&ccnt[c], 1.f);
}

__global__ void means_kernel(const float* __restrict__ csums,
                             const float* __restrict__ ccnt,
                             float* __restrict__ means)
{
    int c = blockIdx.x * 256 + threadIdx.x;
    if (c >= NC) return;
    float cv = fmaxf(ccnt[c], 1.f);
    float v[EMBD];
    float ss = 0.f;
#pragma unroll
    for (int j = 0; j < EMBD; ++j) {
        v[j] = csums[(size_t)c * EMBD + j] / cv;
        ss += v[j] * v[j];
    }
    float inv = 1.f / fmaxf(sqrtf(ss), 1e-12f);
#pragma unroll
    for (int j = 0; j < EMBD; ++j) means[(size_t)c * EMBD + j] = v[j] * inv;
}

// ---------------------------------------------------------------------------
__device__ __forceinline__ void block_stats(float x, float* s_sum, float* s_sumsq)
{
    float x2 = x * x;
#pragma unroll
    for (int s = 32; s >= 1; s >>= 1) {
        x += __shfl_xor(x, s, 64);
        x2 += __shfl_xor(x2, s, 64);
    }
    __shared__ float w0[4], w1[4];
    int lane = threadIdx.x & 63, w = threadIdx.x >> 6;
    if (lane == 0) { w0[w] = x; w1[w] = x2; }
    __syncthreads();
    if (threadIdx.x == 0) {
        float a = 0.f, b = 0.f;
        for (int i = 0; i < 4; ++i) { a += w0[i]; b += w1[i]; }
        atomicAdd(s_sum, a);
        atomicAdd(s_sumsq, b);
    }
}

__global__ __launch_bounds__(256) void sg_lik_kernel(
    const float* __restrict__ means, const int* __restrict__ sg0,
    const int* __restrict__ sg1, float* __restrict__ sg_lik, float* __restrict__ stats)
{
    int e = blockIdx.x * 256 + threadIdx.x;
    float x = 0.f;
    if (e < NES) {
        const float* a = means + (size_t)sg0[e] * EMBD;
        const float* b = means + (size_t)sg1[e] * EMBD;
        float s = 0.f;
#pragma unroll
        for (int j = 0; j < EMBD; ++j) s += a[j] * b[j];
        sg_lik[e] = s;
        x = s;
    }
    block_stats(x, &stats[0], &stats[1]);
}

__global__ __launch_bounds__(256) void sgw_kernel(
    const float* __restrict__ sg_lik, const float* __restrict__ stats,
    const float* __restrict__ gamma, const float* __restrict__ beta,
    float* __restrict__ out)
{
    int e = blockIdx.x * 256 + threadIdx.x;
    if (e >= NES) return;
    float m = stats[0] / (float)NES;
    float var = stats[1] / (float)NES - m * m;
    float y = (sg_lik[e] - m) * rsqrtf(var + 1e-5f) * gamma[0] + beta[0];
    out[e] = 1.f / (1.f + __expf(-y));
}

__global__ __launch_bounds__(256) void bg_lik_kernel(
    const float* __restrict__ emb, const float* __restrict__ means,
    const int* __restrict__ bg_src, const int* __restrict__ bg_dst,
    float* __restrict__ bg_lik, float* __restrict__ stats)
{
    int e = blockIdx.x * 256 + threadIdx.x;
    float x = 0.f;
    if (e < NEB) {
        const float* a = emb + (size_t)bg_src[e] * EMBD;
        const float* b = means + (size_t)bg_dst[e] * EMBD;
        float s = 0.f;
#pragma unroll
        for (int j = 0; j < EMBD; ++j) s += a[j] * b[j];
        bg_lik[e] = s;
        x = s;
    }
    block_stats(x, &stats[2], &stats[3]);
}

__global__ __launch_bounds__(256) void bw_kernel(
    const float* __restrict__ bg_lik, const float* __restrict__ stats,
    const float* __restrict__ gamma, const float* __restrict__ beta,
    const int* __restrict__ bg_src, float* __restrict__ bw, float* __restrict__ denom)
{
    int e = blockIdx.x * 256 + threadIdx.x;
    if (e >= NEB) return;
    float m = stats[2] / (float)NEB;
    float var = stats[3] / (float)NEB - m * m;
    float y = (bg_lik[e] - m) * rsqrtf(var + 1e-5f) * gamma[0] + beta[0];
    float w = __expf(y);
    bw[e] = w;
    atomicAdd(&denom[bg_src[e]], w);
}

__global__ __launch_bounds__(256) void bw_norm_kernel(
    float* __restrict__ bw, const float* __restrict__ denom,
    const int* __restrict__ bg_src, float* __restrict__ out)
{
    int e = blockIdx.x * 256 + threadIdx.x;
    if (e >= NEB) return;
    float w = bw[e] / (1e-12f + denom[bg_src[e]]);
    bw[e] = w;
    out[e] = w;
}

// ---------------------------------------------------------------------------
__global__ void hist_kernel(const int* __restrict__ bg_dst, int* __restrict__ cnt)
{
    int e = blockIdx.x * 256 + threadIdx.x;
    if (e >= NEB) return;
    atomicAdd(&cnt[bg_dst[e]], 1);
}

__global__ __launch_bounds__(1024) void scan_kernel(
    const int* __restrict__ cnt, int* __restrict__ offs, int C)
{
    __shared__ int wsum[16];
    __shared__ int carry_s, ctot_s;
    const int tid = threadIdx.x;
    const int lane = tid & 63, w = tid >> 6;
    if (tid == 0) carry_s = 0;
    __syncthreads();
    for (int base = 0; base < C; base += 1024) {
        int i = base + tid;
        int v = (i < C) ? cnt[i] : 0;
        int x = v;
#pragma unroll
        for (int s = 1; s < 64; s <<= 1) {
            int y = __shfl_up(x, s, 64);
            if (lane >= s) x += y;
        }
        if (lane == 63) wsum[w] = x;
        __syncthreads();
        if (tid == 0) {
            int s = 0;
            for (int k = 0; k < 16; ++k) { int t = wsum[k]; wsum[k] = s; s += t; }
            ctot_s = s;
        }
        __syncthreads();
        int excl = carry_s + wsum[w] + (x - v);
        if (i < C) offs[i] = excl;
        __syncthreads();
        if (tid == 0) carry_s += ctot_s;
        __syncthreads();
    }
    if (tid == 0) offs[C] = carry_s;
}

__global__ void scatter_kernel(const int* __restrict__ bg_dst,
                               const int* __restrict__ offs,
                               int* __restrict__ fill, int* __restrict__ eids)
{
    int e = blockIdx.x * 256 + threadIdx.x;
    if (e >= NEB) return;
    int d = bg_dst[e];
    int p = atomicAdd(&fill[d], 1);
    eids[offs[d] + p] = e;
}

// ---------------------------------------------------------------------------
// supernodes[c][:] = sum_{e: bg_dst[e]==c} bw[e]*nmsg[bg_src[e]][:]  (nmsg bf16)
// ---------------------------------------------------------------------------
__global__ __launch_bounds__(128) void supernodes_kernel(
    const ushort_t* __restrict__ nmsg, const float* __restrict__ bw,
    const int* __restrict__ bg_src, const int* __restrict__ eids,
    const int* __restrict__ offs, float* __restrict__ sn)
{
    int c = blockIdx.x;
    int t = threadIdx.x;
    int beg = offs[c], end = offs[c + 1];
    float acc = 0.f;
    for (int p = beg; p < end; ++p) {
        int e = eids[p];
        int s = bg_src[e];
        float w = bw[e];
        acc += w * bf2f(nmsg[(size_t)s * LATD + t]);
    }
    sn[(size_t)c * LATD + t] = acc;
}

// ---------------------------------------------------------------------------
extern "C" void kernel_launch(void* const* d_in, const int* in_sizes, int n_in,
                              void* d_out, int out_size, void* d_ws, size_t ws_size,
                              hipStream_t stream)
{
    const float* emb_nodes = (const float*)d_in[0];
    const float* enc_nodes = (const float*)d_in[1];
    const float* Wc1 = (const float*)d_in[2];  const float* bc1 = (const float*)d_in[3];
    const float* Wc2 = (const float*)d_in[4];  const float* bc2 = (const float*)d_in[5];
    const float* Wc3 = (const float*)d_in[6];  const float* bc3 = (const float*)d_in[7];
    const float* Wn1 = (const float*)d_in[8];  const float* cn1 = (const float*)d_in[9];
    const float* Wn2 = (const float*)d_in[10]; const float* cn2 = (const float*)d_in[11];
    const float* We1 = (const float*)d_in[12]; const float* ce1 = (const float*)d_in[13];
    const float* We2 = (const float*)d_in[14]; const float* ce2 = (const float*)d_in[15];
    const float* sg_gamma = (const float*)d_in[16]; const float* sg_beta = (const float*)d_in[17];
    const float* bg_gamma = (const float*)d_in[18]; const float* bg_beta = (const float*)d_in[19];
    const int* clusters = (const int*)d_in[20];
    const int* sg0 = (const int*)d_in[21];
    const int* sg1 = sg0 + NES;
    const int* bg_src = (const int*)d_in[22];
    const int* bg_dst = (const int*)d_in[23];

    // output layout (flat, return order)
    float* out_emb = (float*)d_out;                       // NN*EMBD
    float* out_sn  = out_emb + (size_t)NN * EMBD;         // NC*LATD
    float* out_se  = out_sn + (size_t)NC * LATD;          // NES*LATD
    float* out_bw  = out_se + (size_t)NES * LATD;         // NEB
    float* out_sew = out_bw + (size_t)NEB;                // NES

    // ---------------- workspace layout (byte cursor, 64B-aligned) ----------
    uintptr_t cur = (uintptr_t)d_ws;
    uintptr_t wend = cur + ws_size;
    auto alloc = [&](size_t bytes) -> void* {
        cur = (cur + 63) & ~(uintptr_t)63;
        void* p = (void*)cur;
        cur += bytes;
        return p;
    };

    // zeroed region (contiguous)
    float* zbase = (float*)alloc(((size_t)NC * EMBD + NC + NN + 8 + NC + NC) * 4);
    float* csums = zbase;
    float* ccnt  = csums + (size_t)NC * EMBD;
    float* denom = ccnt + NC;
    float* stats = denom + NN;
    int*   cnt   = (int*)(stats + 8);
    int*   fill  = cnt + NC;
    size_t zero_bytes = ((size_t)NC * EMBD + NC + NN + 8 + NC + NC) * 4;

    float* means  = (float*)alloc((size_t)NC * EMBD * 4);
    float* sg_lik = (float*)alloc((size_t)NES * 4);
    float* bg_lik = (float*)alloc((size_t)NEB * 4);
    float* bwv    = (float*)alloc((size_t)NEB * 4);
    int*   offs   = (int*)alloc((size_t)(NC + 1) * 4);
    int*   eids   = (int*)alloc((size_t)NEB * 4);

    ushort_t* xemb   = (ushort_t*)alloc((size_t)NN * LATD * 2);
    ushort_t* xenc   = (ushort_t*)alloc((size_t)NN * LATD * 2);
    ushort_t* nmsgb  = (ushort_t*)alloc((size_t)NN * LATD * 2);
    ushort_t* sn_bf  = (ushort_t*)alloc((size_t)NC * LATD * 2);
    ushort_t* Wc1t = (ushort_t*)alloc((size_t)LATD * HIDD * 2);
    ushort_t* Wc2t = (ushort_t*)alloc((size_t)HIDD * HIDD * 2);
    ushort_t* Wn1t = (ushort_t*)alloc((size_t)LATD * HIDD * 2);
    ushort_t* Wn2t = (ushort_t*)alloc((size_t)HIDD * LATD * 2);
    ushort_t* We1t = (ushort_t*)alloc((size_t)2 * LATD * HIDD * 2);
    ushort_t* We2t = (ushort_t*)alloc((size_t)HIDD * LATD * 2);

    cur = (cur + 63) & ~(uintptr_t)63;
    size_t rem_bytes = (wend > cur) ? (size_t)(wend - cur) : 0;
    size_t chunk_sz = (rem_bytes / (2 * (size_t)HIDD * 2)) & ~(size_t)63;
    if (chunk_sz > 51200) chunk_sz = 51200;
    if (chunk_sz < 256) return;  // fail soft
    const int CH = (int)chunk_sz;
    ushort_t* bufA = (ushort_t*)cur;
    ushort_t* bufB = bufA + (size_t)CH * HIDD;

    hipMemsetAsync(zbase, 0, zero_bytes, stream);

    dim3 blk(256);

    // ---- prep: input/weight conversions ----
    conv_f2b_kernel<<<2048, blk, 0, stream>>>(emb_nodes, xemb, (long)NN * LATD);
    conv_f2b_kernel<<<2048, blk, 0, stream>>>(enc_nodes, xenc, (long)NN * LATD);
    transpose_conv_kernel<<<(LATD * HIDD + 255) / 256, blk, 0, stream>>>(Wc1, Wc1t, LATD, HIDD);
    transpose_conv_kernel<<<(HIDD * HIDD + 255) / 256, blk, 0, stream>>>(Wc2, Wc2t, HIDD, HIDD);
    transpose_conv_kernel<<<(LATD * HIDD + 255) / 256, blk, 0, stream>>>(Wn1, Wn1t, LATD, HIDD);
    transpose_conv_kernel<<<(HIDD * LATD + 255) / 256, blk, 0, stream>>>(Wn2, Wn2t, HIDD, LATD);
    transpose_conv_kernel<<<(2 * LATD * HIDD + 255) / 256, blk, 0, stream>>>(We1, We1t, 2 * LATD, HIDD);
    transpose_conv_kernel<<<(HIDD * LATD + 255) / 256, blk, 0, stream>>>(We2, We2t, HIDD, LATD);

    // ---- fused node chain, chunked: xemb->h1->h2->embeddings ----
    for (int m0 = 0; m0 < NN; m0 += CH) {
        int cm = (NN - m0 < CH) ? (NN - m0) : CH;
        gemm_mfma<ACT_TANH, false, true><<<dim3(HIDD / 128, (cm + 127) / 128), blk, 0, stream>>>(
            xemb + (size_t)m0 * LATD, Wc1t, bc1, bufA, cm, HIDD, LATD, nullptr, nullptr, nullptr);
        gemm_mfma<ACT_TANH, false, true><<<dim3(HIDD / 128, (cm + 127) / 128), blk, 0, stream>>>(
            bufA, Wc2t, bc2, bufB, cm, HIDD, HIDD, nullptr, nullptr, nullptr);
        emb_kernel<<<(cm + 3) / 4, blk, 0, stream>>>(
            bufB, Wc3, bc3, out_emb + (size_t)m0 * EMBD, cm);
    }

    // ---- cluster means ----
    cluster_accum<<<(NN * EMBD + 255) / 256, blk, 0, stream>>>(out_emb, clusters, csums, ccnt);
    means_kernel<<<(NC + 255) / 256, blk, 0, stream>>>(csums, ccnt, means);

    // ---- super edge weights ----
    sg_lik_kernel<<<(NES + 255) / 256, blk, 0, stream>>>(means, sg0, sg1, sg_lik, stats);
    sgw_kernel<<<(NES + 255) / 256, blk, 0, stream>>>(sg_lik, stats, sg_gamma, sg_beta, out_sew);

    // ---- bipartite edge weights ----
    bg_lik_kernel<<<(NEB + 255) / 256, blk, 0, stream>>>(out_emb, means, bg_src, bg_dst, bg_lik, stats);
    bw_kernel<<<(NEB + 255) / 256, blk, 0, stream>>>(bg_lik, stats, bg_gamma, bg_beta, bg_src, bwv, denom);
    bw_norm_kernel<<<(NEB + 255) / 256, blk, 0, stream>>>(bwv, denom, bg_src, out_bw);

    // ---- counting sort of edges by destination cluster ----
    hist_kernel<<<(NEB + 255) / 256, blk, 0, stream>>>(bg_dst, cnt);
    scan_kernel<<<1, 1024, 0, stream>>>(cnt, offs, NC);
    scatter_kernel<<<(NEB + 255) / 256, blk, 0, stream>>>(bg_dst, offs, fill, eids);

    // ---- node messages, chunked: xenc->nm->nmsg(bf16, full) ----
    for (int m0 = 0; m0 < NN; m0 += CH) {
        int cm = (NN - m0 < CH) ? (NN - m0) : CH;
        gemm_mfma<ACT_RELU, false, true><<<dim3(HIDD / 128, (cm + 127) / 128), blk, 0, stream>>>(
            xenc + (size_t)m0 * LATD, Wn1t, cn1, bufA, cm, HIDD, LATD, nullptr, nullptr, nullptr);
        gemm_mfma<ACT_RELU, false, true><<<dim3(LATD / 128, (cm + 127) / 128), blk, 0, stream>>>(
            bufA, Wn2t, cn2, nmsgb + (size_t)m0 * LATD, cm, LATD, HIDD, nullptr, nullptr, nullptr);
    }

    // ---- supernodes (sorted edge lists, no atomics) ----
    supernodes_kernel<<<NC, 128, 0, stream>>>(nmsgb, bwv, bg_src, eids, offs, out_sn);
    conv_f2b_kernel<<<512, blk, 0, stream>>>(out_sn, sn_bf, (long)NC * LATD);

    // ---- superedges, chunked (bufA+bufB = one 2*CH-row region) ----
    const int CE = 2 * CH;
    for (int e0 = 0; e0 < NES; e0 += CE) {
        int ce = (NES - e0 < CE) ? (NES - e0) : CE;
        gemm_mfma<ACT_RELU, true, true><<<dim3(HIDD / 128, (ce + 127) / 128), blk, 0, stream>>>(
            nullptr, We1t, ce1, bufA, ce, HIDD, 2 * LATD, sg0 + e0, sg1 + e0, sn_bf);
        gemm_mfma<ACT_RELU, false, false><<<dim3(LATD / 128, (ce + 127) / 128), blk, 0, stream>>>(
            bufA, We2t, ce2, out_se + (size_t)e0 * LATD, ce, LATD, HIDD, nullptr, nullptr, nullptr);
    }
}

// Round 4
// 1265.754 us; speedup vs baseline: 2.3917x; 1.0794x over previous
//
#include <hip/hip_runtime.h>
#include <cstdint>
#include <cstddef>

// Problem constants (SuperGraphConstruction)
#define NN 100000      // nodes
#define NC 20000       // clusters
#define LATD 128
#define HIDD 512
#define EMBD 12
#define NES 160000     // super edges
#define NEB 800000     // bipartite edges

enum { ACT_NONE = 0, ACT_TANH = 1, ACT_RELU = 2 };

typedef __attribute__((ext_vector_type(8))) short bf16x8;
typedef __attribute__((ext_vector_type(4))) float f32x4;
typedef unsigned short ushort_t;

__device__ __forceinline__ float fast_tanh(float x) {
    return 1.f - 2.f / (__expf(2.f * x) + 1.f);
}
__device__ __forceinline__ ushort_t f2bf(float f) {
    union { float f; unsigned u; } x; x.f = f;
    unsigned r = x.u + 0x7FFFu + ((x.u >> 16) & 1u);  // RNE
    return (ushort_t)(r >> 16);
}
__device__ __forceinline__ float bf2f(ushort_t h) {
    union { unsigned u; float f; } x; x.u = ((unsigned)h) << 16;
    return x.f;
}

typedef __attribute__((address_space(1))) void gvoid_t;
typedef __attribute__((address_space(3))) void svoid_t;
__device__ __forceinline__ void gload_lds16(const void* g, void* l) {
    // async global->LDS, 16B/lane; LDS dest = wave-uniform base + lane*16
    __builtin_amdgcn_global_load_lds((gvoid_t*)g, (svoid_t*)l, 16, 0, 0);
}

// ---------------------------------------------------------------------------
// fp32 -> bf16 elementwise (n multiple of 8 assumed at call sites)
// ---------------------------------------------------------------------------
__global__ __launch_bounds__(256) void conv_f2b_kernel(
    const float* __restrict__ in, ushort_t* __restrict__ out, long n)
{
    long i = ((long)blockIdx.x * 256 + threadIdx.x) * 8;
    long stride = (long)gridDim.x * 256 * 8;
    for (; i + 7 < n; i += stride) {
        float4 a = *(const float4*)(in + i);
        float4 b = *(const float4*)(in + i + 4);
        ushort_t o[8] = { f2bf(a.x), f2bf(a.y), f2bf(a.z), f2bf(a.w),
                          f2bf(b.x), f2bf(b.y), f2bf(b.z), f2bf(b.w) };
        *(int4*)(out + i) = *(int4*)o;
    }
}

// W [K][N] fp32 -> Wt [N][K] bf16  (small, launched per weight)
__global__ __launch_bounds__(256) void transpose_conv_kernel(
    const float* __restrict__ W, ushort_t* __restrict__ Wt, int K, int N)
{
    int i = blockIdx.x * 256 + threadIdx.x;
    if (i >= K * N) return;
    int n = i / K, k = i % K;
    Wt[i] = f2bf(W[(size_t)k * N + n]);
}

// ---------------------------------------------------------------------------
// bf16 MFMA GEMM (m97 structure): C[M,N] = act(A[M,K] @ B[K,N] + bias)
//   A bf16 row-major [M][K]; Bt bf16 PRE-TRANSPOSED [N][K]; bias fp32.
//   GATHER: A row m = concat(gsrc[g0[m]][0:128], gsrc[g1[m]][0:128]), K=256.
//   BM=BN=128, BK=64; 256 threads = 4 waves (2x2); each wave 64x64 out.
//   Staging via global_load_lds(16B), LINEAR LDS [128][64] (no pad).
//   N multiple of 128, K multiple of 64. M-tail: source row clamped.
// ---------------------------------------------------------------------------
template<int ACT, bool GATHER, bool OUT_BF16>
__global__ __launch_bounds__(256) void gemm_mfma(
    const ushort_t* __restrict__ A, const ushort_t* __restrict__ Bt,
    const float* __restrict__ bias, void* __restrict__ Cv,
    int M, int N, int K,
    const int* __restrict__ g0, const int* __restrict__ g1,
    const ushort_t* __restrict__ gsrc)
{
    __shared__ ushort_t As[128 * 64];   // linear: row*64 + col
    __shared__ ushort_t Bs[128 * 64];

    const int tid = threadIdx.x;
    const int m0 = blockIdx.y * 128, n0 = blockIdx.x * 128;
    const int w = tid >> 6, lane = tid & 63;
    const int wm = w >> 1, wn = w & 1;
    const int lr = lane & 15, lg = lane >> 4;
    const int lrow = lane >> 3;        // 0..7 row within 8-row chunk
    const int lcol = (lane & 7) * 8;   // bf16 col within 64-col row

    f32x4 acc[4][4];
#pragma unroll
    for (int i = 0; i < 4; ++i)
#pragma unroll
        for (int j = 0; j < 4; ++j) acc[i][j] = (f32x4){0.f, 0.f, 0.f, 0.f};

    for (int k0 = 0; k0 < K; k0 += 64) {
        // ---- stage tiles: each wave issues 4 A-chunks + 4 B-chunks (1KB each)
#pragma unroll
        for (int i = 0; i < 4; ++i) {
            int c = w * 4 + i;            // chunk 0..15 (8 rows each)
            int row = c * 8 + lrow;       // tile row 0..127
            int gm = m0 + row; if (gm >= M) gm = M - 1;  // clamp tail
            const ushort_t* ga;
            if (!GATHER) {
                ga = A + (size_t)gm * K + k0 + lcol;
            } else {
                int src = (k0 >= LATD) ? g1[gm] : g0[gm];
                ga = gsrc + (size_t)src * LATD + (k0 & (LATD - 1)) + lcol;
            }
            gload_lds16(ga, As + c * 512);
            const ushort_t* gb = Bt + (size_t)(n0 + row) * K + k0 + lcol;
            gload_lds16(gb, Bs + c * 512);
        }
        __syncthreads();

        // ---- 2 k-steps of 32 ----
#pragma unroll
        for (int ks = 0; ks < 2; ++ks) {
            bf16x8 af[4], bf[4];
#pragma unroll
            for (int mt = 0; mt < 4; ++mt)
                af[mt] = *(const bf16x8*)&As[(wm * 64 + mt * 16 + lr) * 64 + ks * 32 + lg * 8];
#pragma unroll
            for (int nt = 0; nt < 4; ++nt)
                bf[nt] = *(const bf16x8*)&Bs[(wn * 64 + nt * 16 + lr) * 64 + ks * 32 + lg * 8];
#pragma unroll
            for (int mt = 0; mt < 4; ++mt)
#pragma unroll
                for (int nt = 0; nt < 4; ++nt)
                    acc[mt][nt] = __builtin_amdgcn_mfma_f32_16x16x32_bf16(
                        af[mt], bf[nt], acc[mt][nt], 0, 0, 0);
        }
        __syncthreads();
    }

    // ---- epilogue: D lane,reg -> row=(lane>>4)*4+reg, col=lane&15 ----
#pragma unroll
    for (int nt = 0; nt < 4; ++nt) {
        int col = n0 + wn * 64 + nt * 16 + lr;
        float bv = bias[col];
#pragma unroll
        for (int mt = 0; mt < 4; ++mt) {
#pragma unroll
            for (int r = 0; r < 4; ++r) {
                int row = m0 + wm * 64 + mt * 16 + lg * 4 + r;
                if (row >= M) continue;
                float v = acc[mt][nt][r] + bv;
                if (ACT == ACT_TANH) v = fast_tanh(v);
                else if (ACT == ACT_RELU) v = fmaxf(v, 0.f);
                if (OUT_BF16) ((ushort_t*)Cv)[(size_t)row * N + col] = f2bf(v);
                else ((float*)Cv)[(size_t)row * N + col] = v;
            }
        }
    }
}

// ---------------------------------------------------------------------------
// embeddings = l2norm(h2 @ Wc3 + bc3); wave-per-row; h2 is bf16.
// ---------------------------------------------------------------------------
__global__ __launch_bounds__(256) void emb_kernel(
    const ushort_t* __restrict__ h2, const float* __restrict__ W,  // [512][12]
    const float* __restrict__ bias, float* __restrict__ out, int M)
{
    __shared__ float Wl[EMBD][HIDD];  // transposed: Wl[j][k]
    for (int i = threadIdx.x; i < HIDD * EMBD; i += 256) {
        int k = i / EMBD, j = i % EMBD;
        Wl[j][k] = W[i];
    }
    __syncthreads();
    const int wave = threadIdx.x >> 6;
    const int lane = threadIdx.x & 63;
    const int m = blockIdx.x * 4 + wave;
    if (m >= M) return;

    float acc[EMBD] = {};
    const ushort_t* row = h2 + (size_t)m * HIDD;
#pragma unroll
    for (int c = 0; c < HIDD / 64; ++c) {
        float hv = bf2f(row[c * 64 + lane]);
#pragma unroll
        for (int j = 0; j < EMBD; ++j)
            acc[j] += hv * Wl[j][c * 64 + lane];
    }
#pragma unroll
    for (int j = 0; j < EMBD; ++j) {
        float v = acc[j];
#pragma unroll
        for (int s = 32; s >= 1; s >>= 1) v += __shfl_xor(v, s, 64);
        acc[j] = v + bias[j];
    }
    float ss = 0.f;
#pragma unroll
    for (int j = 0; j < EMBD; ++j) ss += acc[j] * acc[j];
    float inv = 1.f / fmaxf(sqrtf(ss), 1e-12f);
    if (lane < EMBD) out[(size_t)m * EMBD + lane] = acc[lane] * inv;
}

// ---------------------------------------------------------------------------
__global__ void cluster_accum(const float* __restrict__ emb,
                              const int* __restrict__ clusters,
                              float* __restrict__ csums, float* __restrict__ ccnt)
{
    int i = blockIdx.x * 256 + threadIdx.x;
    if (i >= NN * EMBD) return;
    int n = i / EMBD, j = i % EMBD;
    int c = clusters[n];
    atomicAdd(&csums[(size_t)c * EMBD + j], emb[i]);
    if (j == 0) atomicAdd(&ccnt[c], 1.f);
}

__global__ void means_kernel(const float* __restrict__ csums,
                             const float* __restrict__ ccnt,
                             float* __restrict__ means)
{
    int c = blockIdx.x * 256 + threadIdx.x;
    if (c >= NC) return;
    float cv = fmaxf(ccnt[c], 1.f);
    float v[EMBD];
    float ss = 0.f;
#pragma unroll
    for (int j = 0; j < EMBD; ++j) {
        v[j] = csums[(size_t)c * EMBD + j] / cv;
        ss += v[j] * v[j];
    }
    float inv = 1.f / fmaxf(sqrtf(ss), 1e-12f);
#pragma unroll
    for (int j = 0; j < EMBD; ++j) means[(size_t)c * EMBD + j] = v[j] * inv;
}

// ---------------------------------------------------------------------------
__device__ __forceinline__ void block_stats(float x, float* s_sum, float* s_sumsq)
{
    float x2 = x * x;
#pragma unroll
    for (int s = 32; s >= 1; s >>= 1) {
        x += __shfl_xor(x, s, 64);
        x2 += __shfl_xor(x2, s, 64);
    }
    __shared__ float w0[4], w1[4];
    int lane = threadIdx.x & 63, w = threadIdx.x >> 6;
    if (lane == 0) { w0[w] = x; w1[w] = x2; }
    __syncthreads();
    if (threadIdx.x == 0) {
        float a = 0.f, b = 0.f;
        for (int i = 0; i < 4; ++i) { a += w0[i]; b += w1[i]; }
        atomicAdd(s_sum, a);
        atomicAdd(s_sumsq, b);
    }
}

__global__ __launch_bounds__(256) void sg_lik_kernel(
    const float* __restrict__ means, const int* __restrict__ sg0,
    const int* __restrict__ sg1, float* __restrict__ sg_lik, float* __restrict__ stats)
{
    int e = blockIdx.x * 256 + threadIdx.x;
    float x = 0.f;
    if (e < NES) {
        const float* a = means + (size_t)sg0[e] * EMBD;
        const float* b = means + (size_t)sg1[e] * EMBD;
        float s = 0.f;
#pragma unroll
        for (int j = 0; j < EMBD; ++j) s += a[j] * b[j];
        sg_lik[e] = s;
        x = s;
    }
    block_stats(x, &stats[0], &stats[1]);
}

__global__ __launch_bounds__(256) void sgw_kernel(
    const float* __restrict__ sg_lik, const float* __restrict__ stats,
    const float* __restrict__ gamma, const float* __restrict__ beta,
    float* __restrict__ out)
{
    int e = blockIdx.x * 256 + threadIdx.x;
    if (e >= NES) return;
    float m = stats[0] / (float)NES;
    float var = stats[1] / (float)NES - m * m;
    float y = (sg_lik[e] - m) * rsqrtf(var + 1e-5f) * gamma[0] + beta[0];
    out[e] = 1.f / (1.f + __expf(-y));
}

// bg_lik + per-dst histogram fused (same 800k-edge pass)
__global__ __launch_bounds__(256) void bg_lik_kernel(
    const float* __restrict__ emb, const float* __restrict__ means,
    const int* __restrict__ bg_src, const int* __restrict__ bg_dst,
    float* __restrict__ bg_lik, float* __restrict__ stats, int* __restrict__ cnt)
{
    int e = blockIdx.x * 256 + threadIdx.x;
    float x = 0.f;
    if (e < NEB) {
        int d = bg_dst[e];
        atomicAdd(&cnt[d], 1);
        const float* a = emb + (size_t)bg_src[e] * EMBD;
        const float* b = means + (size_t)d * EMBD;
        float s = 0.f;
#pragma unroll
        for (int j = 0; j < EMBD; ++j) s += a[j] * b[j];
        bg_lik[e] = s;
        x = s;
    }
    block_stats(x, &stats[2], &stats[3]);
}

__global__ __launch_bounds__(256) void bw_kernel(
    const float* __restrict__ bg_lik, const float* __restrict__ stats,
    const float* __restrict__ gamma, const float* __restrict__ beta,
    const int* __restrict__ bg_src, float* __restrict__ bw, float* __restrict__ denom)
{
    int e = blockIdx.x * 256 + threadIdx.x;
    if (e >= NEB) return;
    float m = stats[2] / (float)NEB;
    float var = stats[3] / (float)NEB - m * m;
    float y = (bg_lik[e] - m) * rsqrtf(var + 1e-5f) * gamma[0] + beta[0];
    float w = __expf(y);
    bw[e] = w;
    atomicAdd(&denom[bg_src[e]], w);
}

__global__ __launch_bounds__(256) void bw_norm_kernel(
    float* __restrict__ bw, const float* __restrict__ denom,
    const int* __restrict__ bg_src, float* __restrict__ out)
{
    int e = blockIdx.x * 256 + threadIdx.x;
    if (e >= NEB) return;
    float w = bw[e] / (1e-12f + denom[bg_src[e]]);
    bw[e] = w;
    out[e] = w;
}

// ---------------------------------------------------------------------------
__global__ __launch_bounds__(1024) void scan_kernel(
    const int* __restrict__ cnt, int* __restrict__ offs, int C)
{
    __shared__ int wsum[16];
    __shared__ int carry_s, ctot_s;
    const int tid = threadIdx.x;
    const int lane = tid & 63, w = tid >> 6;
    if (tid == 0) carry_s = 0;
    __syncthreads();
    for (int base = 0; base < C; base += 1024) {
        int i = base + tid;
        int v = (i < C) ? cnt[i] : 0;
        int x = v;
#pragma unroll
        for (int s = 1; s < 64; s <<= 1) {
            int y = __shfl_up(x, s, 64);
            if (lane >= s) x += y;
        }
        if (lane == 63) wsum[w] = x;
        __syncthreads();
        if (tid == 0) {
            int s = 0;
            for (int k = 0; k < 16; ++k) { int t = wsum[k]; wsum[k] = s; s += t; }
            ctot_s = s;
        }
        __syncthreads();
        int excl = carry_s + wsum[w] + (x - v);
        if (i < C) offs[i] = excl;
        __syncthreads();
        if (tid == 0) carry_s += ctot_s;
        __syncthreads();
    }
    if (tid == 0) offs[C] = carry_s;
}

__global__ void scatter_kernel(const int* __restrict__ bg_dst,
                               const int* __restrict__ offs,
                               int* __restrict__ fill, int* __restrict__ eids)
{
    int e = blockIdx.x * 256 + threadIdx.x;
    if (e >= NEB) return;
    int d = bg_dst[e];
    int p = atomicAdd(&fill[d], 1);
    eids[offs[d] + p] = e;
}

// ---------------------------------------------------------------------------
// supernodes[c][:] = sum_{e: bg_dst[e]==c} bw[e]*nmsg[bg_src[e]][:]  (nmsg bf16)
// x4 unrolled: 4 independent row-gathers in flight per block.
// ---------------------------------------------------------------------------
__global__ __launch_bounds__(128) void supernodes_kernel(
    const ushort_t* __restrict__ nmsg, const float* __restrict__ bw,
    const int* __restrict__ bg_src, const int* __restrict__ eids,
    const int* __restrict__ offs, float* __restrict__ sn)
{
    int c = blockIdx.x;
    int t = threadIdx.x;
    int beg = offs[c], end = offs[c + 1];
    float a0 = 0.f, a1 = 0.f, a2 = 0.f, a3 = 0.f;
    int p = beg;
    for (; p + 3 < end; p += 4) {
        int e0 = eids[p], e1 = eids[p + 1], e2 = eids[p + 2], e3 = eids[p + 3];
        int s0 = bg_src[e0], s1 = bg_src[e1], s2 = bg_src[e2], s3 = bg_src[e3];
        float w0 = bw[e0], w1 = bw[e1], w2 = bw[e2], w3 = bw[e3];
        ushort_t v0 = nmsg[(size_t)s0 * LATD + t];
        ushort_t v1 = nmsg[(size_t)s1 * LATD + t];
        ushort_t v2 = nmsg[(size_t)s2 * LATD + t];
        ushort_t v3 = nmsg[(size_t)s3 * LATD + t];
        a0 += w0 * bf2f(v0);
        a1 += w1 * bf2f(v1);
        a2 += w2 * bf2f(v2);
        a3 += w3 * bf2f(v3);
    }
    for (; p < end; ++p) {
        int e = eids[p];
        a0 += bw[e] * bf2f(nmsg[(size_t)bg_src[e] * LATD + t]);
    }
    sn[(size_t)c * LATD + t] = a0 + a1 + a2 + a3;
}

// ---------------------------------------------------------------------------
extern "C" void kernel_launch(void* const* d_in, const int* in_sizes, int n_in,
                              void* d_out, int out_size, void* d_ws, size_t ws_size,
                              hipStream_t stream)
{
    const float* emb_nodes = (const float*)d_in[0];
    const float* enc_nodes = (const float*)d_in[1];
    const float* Wc1 = (const float*)d_in[2];  const float* bc1 = (const float*)d_in[3];
    const float* Wc2 = (const float*)d_in[4];  const float* bc2 = (const float*)d_in[5];
    const float* Wc3 = (const float*)d_in[6];  const float* bc3 = (const float*)d_in[7];
    const float* Wn1 = (const float*)d_in[8];  const float* cn1 = (const float*)d_in[9];
    const float* Wn2 = (const float*)d_in[10]; const float* cn2 = (const float*)d_in[11];
    const float* We1 = (const float*)d_in[12]; const float* ce1 = (const float*)d_in[13];
    const float* We2 = (const float*)d_in[14]; const float* ce2 = (const float*)d_in[15];
    const float* sg_gamma = (const float*)d_in[16]; const float* sg_beta = (const float*)d_in[17];
    const float* bg_gamma = (const float*)d_in[18]; const float* bg_beta = (const float*)d_in[19];
    const int* clusters = (const int*)d_in[20];
    const int* sg0 = (const int*)d_in[21];
    const int* sg1 = sg0 + NES;
    const int* bg_src = (const int*)d_in[22];
    const int* bg_dst = (const int*)d_in[23];

    // output layout (flat, return order)
    float* out_emb = (float*)d_out;                       // NN*EMBD
    float* out_sn  = out_emb + (size_t)NN * EMBD;         // NC*LATD
    float* out_se  = out_sn + (size_t)NC * LATD;          // NES*LATD
    float* out_bw  = out_se + (size_t)NES * LATD;         // NEB
    float* out_sew = out_bw + (size_t)NEB;                // NES

    // ---------------- workspace layout (byte cursor, 64B-aligned) ----------
    uintptr_t cur = (uintptr_t)d_ws;
    uintptr_t wend = cur + ws_size;
    auto alloc = [&](size_t bytes) -> void* {
        cur = (cur + 63) & ~(uintptr_t)63;
        void* p = (void*)cur;
        cur += bytes;
        return p;
    };

    // zeroed region (contiguous)
    float* zbase = (float*)alloc(((size_t)NC * EMBD + NC + NN + 8 + NC + NC) * 4);
    float* csums = zbase;
    float* ccnt  = csums + (size_t)NC * EMBD;
    float* denom = ccnt + NC;
    float* stats = denom + NN;
    int*   cnt   = (int*)(stats + 8);
    int*   fill  = cnt + NC;
    size_t zero_bytes = ((size_t)NC * EMBD + NC + NN + 8 + NC + NC) * 4;

    float* means  = (float*)alloc((size_t)NC * EMBD * 4);
    float* sg_lik = (float*)alloc((size_t)NES * 4);
    float* bg_lik = (float*)alloc((size_t)NEB * 4);
    float* bwv    = (float*)alloc((size_t)NEB * 4);
    int*   offs   = (int*)alloc((size_t)(NC + 1) * 4);
    int*   eids   = (int*)alloc((size_t)NEB * 4);

    ushort_t* xemb   = (ushort_t*)alloc((size_t)NN * LATD * 2);
    ushort_t* xenc   = (ushort_t*)alloc((size_t)NN * LATD * 2);
    ushort_t* nmsgb  = (ushort_t*)alloc((size_t)NN * LATD * 2);
    ushort_t* sn_bf  = (ushort_t*)alloc((size_t)NC * LATD * 2);
    ushort_t* Wc1t = (ushort_t*)alloc((size_t)LATD * HIDD * 2);
    ushort_t* Wc2t = (ushort_t*)alloc((size_t)HIDD * HIDD * 2);
    ushort_t* Wn1t = (ushort_t*)alloc((size_t)LATD * HIDD * 2);
    ushort_t* Wn2t = (ushort_t*)alloc((size_t)HIDD * LATD * 2);
    ushort_t* We1t = (ushort_t*)alloc((size_t)2 * LATD * HIDD * 2);
    ushort_t* We2t = (ushort_t*)alloc((size_t)HIDD * LATD * 2);

    cur = (cur + 63) & ~(uintptr_t)63;
    size_t rem_bytes = (wend > cur) ? (size_t)(wend - cur) : 0;
    size_t chunk_sz = (rem_bytes / (2 * (size_t)HIDD * 2)) & ~(size_t)127;
    if (chunk_sz > 51200) chunk_sz = 51200;
    if (chunk_sz < 256) return;  // fail soft
    const int CH = (int)chunk_sz;
    ushort_t* bufA = (ushort_t*)cur;
    ushort_t* bufB = bufA + (size_t)CH * HIDD;

    hipMemsetAsync(zbase, 0, zero_bytes, stream);

    dim3 blk(256);

    // ---- prep: input/weight conversions ----
    conv_f2b_kernel<<<2048, blk, 0, stream>>>(emb_nodes, xemb, (long)NN * LATD);
    conv_f2b_kernel<<<2048, blk, 0, stream>>>(enc_nodes, xenc, (long)NN * LATD);
    transpose_conv_kernel<<<(LATD * HIDD + 255) / 256, blk, 0, stream>>>(Wc1, Wc1t, LATD, HIDD);
    transpose_conv_kernel<<<(HIDD * HIDD + 255) / 256, blk, 0, stream>>>(Wc2, Wc2t, HIDD, HIDD);
    transpose_conv_kernel<<<(LATD * HIDD + 255) / 256, blk, 0, stream>>>(Wn1, Wn1t, LATD, HIDD);
    transpose_conv_kernel<<<(HIDD * LATD + 255) / 256, blk, 0, stream>>>(Wn2, Wn2t, HIDD, LATD);
    transpose_conv_kernel<<<(2 * LATD * HIDD + 255) / 256, blk, 0, stream>>>(We1, We1t, 2 * LATD, HIDD);
    transpose_conv_kernel<<<(HIDD * LATD + 255) / 256, blk, 0, stream>>>(We2, We2t, HIDD, LATD);

    // ---- fused node chain, chunked: xemb->h1->h2->embeddings ----
    for (int m0 = 0; m0 < NN; m0 += CH) {
        int cm = (NN - m0 < CH) ? (NN - m0) : CH;
        gemm_mfma<ACT_TANH, false, true><<<dim3(HIDD / 128, (cm + 127) / 128), blk, 0, stream>>>(
            xemb + (size_t)m0 * LATD, Wc1t, bc1, bufA, cm, HIDD, LATD, nullptr, nullptr, nullptr);
        gemm_mfma<ACT_TANH, false, true><<<dim3(HIDD / 128, (cm + 127) / 128), blk, 0, stream>>>(
            bufA, Wc2t, bc2, bufB, cm, HIDD, HIDD, nullptr, nullptr, nullptr);
        emb_kernel<<<(cm + 3) / 4, blk, 0, stream>>>(
            bufB, Wc3, bc3, out_emb + (size_t)m0 * EMBD, cm);
    }

    // ---- cluster means ----
    cluster_accum<<<(NN * EMBD + 255) / 256, blk, 0, stream>>>(out_emb, clusters, csums, ccnt);
    means_kernel<<<(NC + 255) / 256, blk, 0, stream>>>(csums, ccnt, means);

    // ---- super edge weights ----
    sg_lik_kernel<<<(NES + 255) / 256, blk, 0, stream>>>(means, sg0, sg1, sg_lik, stats);
    sgw_kernel<<<(NES + 255) / 256, blk, 0, stream>>>(sg_lik, stats, sg_gamma, sg_beta, out_sew);

    // ---- bipartite edge weights (hist fused into bg_lik) ----
    bg_lik_kernel<<<(NEB + 255) / 256, blk, 0, stream>>>(out_emb, means, bg_src, bg_dst, bg_lik, stats, cnt);
    bw_kernel<<<(NEB + 255) / 256, blk, 0, stream>>>(bg_lik, stats, bg_gamma, bg_beta, bg_src, bwv, denom);
    bw_norm_kernel<<<(NEB + 255) / 256, blk, 0, stream>>>(bwv, denom, bg_src, out_bw);

    // ---- counting sort of edges by destination cluster ----
    scan_kernel<<<1, 1024, 0, stream>>>(cnt, offs, NC);
    scatter_kernel<<<(NEB + 255) / 256, blk, 0, stream>>>(bg_dst, offs, fill, eids);

    // ---- node messages, chunked: xenc->nm->nmsg(bf16, full) ----
    for (int m0 = 0; m0 < NN; m0 += CH) {
        int cm = (NN - m0 < CH) ? (NN - m0) : CH;
        gemm_mfma<ACT_RELU, false, true><<<dim3(HIDD / 128, (cm + 127) / 128), blk, 0, stream>>>(
            xenc + (size_t)m0 * LATD, Wn1t, cn1, bufA, cm, HIDD, LATD, nullptr, nullptr, nullptr);
        gemm_mfma<ACT_RELU, false, true><<<dim3(LATD / 128, (cm + 127) / 128), blk, 0, stream>>>(
            bufA, Wn2t, cn2, nmsgb + (size_t)m0 * LATD, cm, LATD, HIDD, nullptr, nullptr, nullptr);
    }

    // ---- supernodes (sorted edge lists, no atomics) ----
    supernodes_kernel<<<NC, 128, 0, stream>>>(nmsgb, bwv, bg_src, eids, offs, out_sn);
    conv_f2b_kernel<<<512, blk, 0, stream>>>(out_sn, sn_bf, (long)NC * LATD);

    // ---- superedges, chunked (bufA+bufB = one 2*CH-row region) ----
    const int CE = 2 * CH;
    for (int e0 = 0; e0 < NES; e0 += CE) {
        int ce = (NES - e0 < CE) ? (NES - e0) : CE;
        gemm_mfma<ACT_RELU, true, true><<<dim3(HIDD / 128, (ce + 127) / 128), blk, 0, stream>>>(
            nullptr, We1t, ce1, bufA, ce, HIDD, 2 * LATD, sg0 + e0, sg1 + e0, sn_bf);
        gemm_mfma<ACT_RELU, false, false><<<dim3(LATD / 128, (ce + 127) / 128), blk, 0, stream>>>(
            bufA, We2t, ce2, out_se + (size_t)e0 * LATD, ce, LATD, HIDD, nullptr, nullptr, nullptr);
    }
}

// Round 5
// 1108.718 us; speedup vs baseline: 2.7304x; 1.1416x over previous
//
#include <hip/hip_runtime.h>
#include <cstdint>
#include <cstddef>

// Problem constants (SuperGraphConstruction)
#define NN 100000      // nodes
#define NC 20000       // clusters
#define LATD 128
#define HIDD 512
#define EMBD 12
#define NES 160000     // super edges
#define NEB 800000     // bipartite edges

enum { ACT_NONE = 0, ACT_TANH = 1, ACT_RELU = 2 };

typedef __attribute__((ext_vector_type(8))) short bf16x8;
typedef __attribute__((ext_vector_type(4))) float f32x4;
typedef unsigned short ushort_t;

__device__ __forceinline__ float fast_tanh(float x) {
    return 1.f - 2.f / (__expf(2.f * x) + 1.f);
}
__device__ __forceinline__ ushort_t f2bf(float f) {
    union { float f; unsigned u; } x; x.f = f;
    unsigned r = x.u + 0x7FFFu + ((x.u >> 16) & 1u);  // RNE
    return (ushort_t)(r >> 16);
}
__device__ __forceinline__ float bf2f(ushort_t h) {
    union { unsigned u; float f; } x; x.u = ((unsigned)h) << 16;
    return x.f;
}

typedef __attribute__((address_space(1))) void gvoid_t;
typedef __attribute__((address_space(3))) void svoid_t;
__device__ __forceinline__ void gload_lds16(const void* g, void* l) {
    // async global->LDS, 16B/lane; LDS dest = wave-uniform base + lane*16
    __builtin_amdgcn_global_load_lds((gvoid_t*)g, (svoid_t*)l, 16, 0, 0);
}

// ---------------------------------------------------------------------------
// fp32 -> bf16 elementwise (n multiple of 8 assumed at call sites)
// ---------------------------------------------------------------------------
__global__ __launch_bounds__(256) void conv_f2b_kernel(
    const float* __restrict__ in, ushort_t* __restrict__ out, long n)
{
    long i = ((long)blockIdx.x * 256 + threadIdx.x) * 8;
    long stride = (long)gridDim.x * 256 * 8;
    for (; i + 7 < n; i += stride) {
        float4 a = *(const float4*)(in + i);
        float4 b = *(const float4*)(in + i + 4);
        ushort_t o[8] = { f2bf(a.x), f2bf(a.y), f2bf(a.z), f2bf(a.w),
                          f2bf(b.x), f2bf(b.y), f2bf(b.z), f2bf(b.w) };
        *(int4*)(out + i) = *(int4*)o;
    }
}

// W [K][N] fp32 -> Wt [N][K] bf16  (small, launched per weight)
__global__ __launch_bounds__(256) void transpose_conv_kernel(
    const float* __restrict__ W, ushort_t* __restrict__ Wt, int K, int N)
{
    int i = blockIdx.x * 256 + threadIdx.x;
    if (i >= K * N) return;
    int n = i / K, k = i % K;
    Wt[i] = f2bf(W[(size_t)k * N + n]);
}

// ---------------------------------------------------------------------------
// bf16 MFMA GEMM (m97 structure): C[M,N] = act(A[M,K] @ B[K,N] + bias)
//   A bf16 row-major [M][K]; Bt bf16 PRE-TRANSPOSED [N][K]; bias fp32.
//   GATHER: A row m = concat(gsrc[g0[m]][0:128], gsrc[g1[m]][0:128]), K=256.
//   BM=BN=128, BK=64; 256 threads = 4 waves (2x2); each wave 64x64 out.
//   Staging via global_load_lds(16B), LINEAR LDS [128][64] (no pad).
//   N multiple of 128, K multiple of 64. M-tail: source row clamped.
// ---------------------------------------------------------------------------
template<int ACT, bool GATHER, bool OUT_BF16>
__global__ __launch_bounds__(256) void gemm_mfma(
    const ushort_t* __restrict__ A, const ushort_t* __restrict__ Bt,
    const float* __restrict__ bias, void* __restrict__ Cv,
    int M, int N, int K,
    const int* __restrict__ g0, const int* __restrict__ g1,
    const ushort_t* __restrict__ gsrc)
{
    __shared__ ushort_t As[128 * 64];   // linear: row*64 + col
    __shared__ ushort_t Bs[128 * 64];

    const int tid = threadIdx.x;
    const int m0 = blockIdx.y * 128, n0 = blockIdx.x * 128;
    const int w = tid >> 6, lane = tid & 63;
    const int wm = w >> 1, wn = w & 1;
    const int lr = lane & 15, lg = lane >> 4;
    const int lrow = lane >> 3;        // 0..7 row within 8-row chunk
    const int lcol = (lane & 7) * 8;   // bf16 col within 64-col row

    f32x4 acc[4][4];
#pragma unroll
    for (int i = 0; i < 4; ++i)
#pragma unroll
        for (int j = 0; j < 4; ++j) acc[i][j] = (f32x4){0.f, 0.f, 0.f, 0.f};

    for (int k0 = 0; k0 < K; k0 += 64) {
        // ---- stage tiles: each wave issues 4 A-chunks + 4 B-chunks (1KB each)
#pragma unroll
        for (int i = 0; i < 4; ++i) {
            int c = w * 4 + i;            // chunk 0..15 (8 rows each)
            int row = c * 8 + lrow;       // tile row 0..127
            int gm = m0 + row; if (gm >= M) gm = M - 1;  // clamp tail
            const ushort_t* ga;
            if (!GATHER) {
                ga = A + (size_t)gm * K + k0 + lcol;
            } else {
                int src = (k0 >= LATD) ? g1[gm] : g0[gm];
                ga = gsrc + (size_t)src * LATD + (k0 & (LATD - 1)) + lcol;
            }
            gload_lds16(ga, As + c * 512);
            const ushort_t* gb = Bt + (size_t)(n0 + row) * K + k0 + lcol;
            gload_lds16(gb, Bs + c * 512);
        }
        __syncthreads();

        // ---- 2 k-steps of 32 ----
#pragma unroll
        for (int ks = 0; ks < 2; ++ks) {
            bf16x8 af[4], bf[4];
#pragma unroll
            for (int mt = 0; mt < 4; ++mt)
                af[mt] = *(const bf16x8*)&As[(wm * 64 + mt * 16 + lr) * 64 + ks * 32 + lg * 8];
#pragma unroll
            for (int nt = 0; nt < 4; ++nt)
                bf[nt] = *(const bf16x8*)&Bs[(wn * 64 + nt * 16 + lr) * 64 + ks * 32 + lg * 8];
#pragma unroll
            for (int mt = 0; mt < 4; ++mt)
#pragma unroll
                for (int nt = 0; nt < 4; ++nt)
                    acc[mt][nt] = __builtin_amdgcn_mfma_f32_16x16x32_bf16(
                        af[mt], bf[nt], acc[mt][nt], 0, 0, 0);
        }
        __syncthreads();
    }

    // ---- epilogue: D lane,reg -> row=(lane>>4)*4+reg, col=lane&15 ----
#pragma unroll
    for (int nt = 0; nt < 4; ++nt) {
        int col = n0 + wn * 64 + nt * 16 + lr;
        float bv = bias[col];
#pragma unroll
        for (int mt = 0; mt < 4; ++mt) {
#pragma unroll
            for (int r = 0; r < 4; ++r) {
                int row = m0 + wm * 64 + mt * 16 + lg * 4 + r;
                if (row >= M) continue;
                float v = acc[mt][nt][r] + bv;
                if (ACT == ACT_TANH) v = fast_tanh(v);
                else if (ACT == ACT_RELU) v = fmaxf(v, 0.f);
                if (OUT_BF16) ((ushort_t*)Cv)[(size_t)row * N + col] = f2bf(v);
                else ((float*)Cv)[(size_t)row * N + col] = v;
            }
        }
    }
}

// ---------------------------------------------------------------------------
// embeddings = l2norm(h2 @ Wc3 + bc3); THREAD-per-row; h2 bf16.
// Wc3 [512][12] fp32 staged linearly in LDS; reads are wave-broadcast
// (all lanes same address) -> zero bank conflicts, zero shuffles.
// ---------------------------------------------------------------------------
__global__ __launch_bounds__(256) void emb_kernel(
    const ushort_t* __restrict__ h2, const float* __restrict__ W,  // [512][12]
    const float* __restrict__ bias, float* __restrict__ out, int M)
{
    __shared__ float Wl[HIDD * EMBD];  // same layout as W (row-major [k][j])
    for (int i = threadIdx.x; i < HIDD * EMBD; i += 256) Wl[i] = W[i];
    __syncthreads();

    int m = blockIdx.x * 256 + threadIdx.x;
    if (m >= M) return;
    const ushort_t* row = h2 + (size_t)m * HIDD;

    float acc[EMBD] = {};
#pragma unroll 2
    for (int k0 = 0; k0 < HIDD; k0 += 8) {
        bf16x8 v = *(const bf16x8*)(row + k0);
        float f[8];
#pragma unroll
        for (int u = 0; u < 8; ++u) f[u] = bf2f((ushort_t)v[u]);
#pragma unroll
        for (int u = 0; u < 8; ++u) {
            const float* wr = &Wl[(k0 + u) * EMBD];
#pragma unroll
            for (int j = 0; j < EMBD; ++j) acc[j] += f[u] * wr[j];
        }
    }
    float vv[EMBD];
    float ss = 0.f;
#pragma unroll
    for (int j = 0; j < EMBD; ++j) { vv[j] = acc[j] + bias[j]; ss += vv[j] * vv[j]; }
    float inv = 1.f / fmaxf(sqrtf(ss), 1e-12f);
#pragma unroll
    for (int j = 0; j < EMBD; ++j) out[(size_t)m * EMBD + j] = vv[j] * inv;
}

// ---------------------------------------------------------------------------
__global__ void cluster_accum(const float* __restrict__ emb,
                              const int* __restrict__ clusters,
                              float* __restrict__ csums, float* __restrict__ ccnt)
{
    int i = blockIdx.x * 256 + threadIdx.x;
    if (i >= NN * EMBD) return;
    int n = i / EMBD, j = i % EMBD;
    int c = clusters[n];
    atomicAdd(&csums[(size_t)c * EMBD + j], emb[i]);
    if (j == 0) atomicAdd(&ccnt[c], 1.f);
}

__global__ void means_kernel(const float* __restrict__ csums,
                             const float* __restrict__ ccnt,
                             float* __restrict__ means)
{
    int c = blockIdx.x * 256 + threadIdx.x;
    if (c >= NC) return;
    float cv = fmaxf(ccnt[c], 1.f);
    float v[EMBD];
    float ss = 0.f;
#pragma unroll
    for (int j = 0; j < EMBD; ++j) {
        v[j] = csums[(size_t)c * EMBD + j] / cv;
        ss += v[j] * v[j];
    }
    float inv = 1.f / fmaxf(sqrtf(ss), 1e-12f);
#pragma unroll
    for (int j = 0; j < EMBD; ++j) means[(size_t)c * EMBD + j] = v[j] * inv;
}

// ---------------------------------------------------------------------------
__device__ __forceinline__ void block_stats(float x, float* s_sum, float* s_sumsq)
{
    float x2 = x * x;
#pragma unroll
    for (int s = 32; s >= 1; s >>= 1) {
        x += __shfl_xor(x, s, 64);
        x2 += __shfl_xor(x2, s, 64);
    }
    __shared__ float w0[4], w1[4];
    int lane = threadIdx.x & 63, w = threadIdx.x >> 6;
    if (lane == 0) { w0[w] = x; w1[w] = x2; }
    __syncthreads();
    if (threadIdx.x == 0) {
        float a = 0.f, b = 0.f;
        for (int i = 0; i < 4; ++i) { a += w0[i]; b += w1[i]; }
        atomicAdd(s_sum, a);
        atomicAdd(s_sumsq, b);
    }
}

__global__ __launch_bounds__(256) void sg_lik_kernel(
    const float* __restrict__ means, const int* __restrict__ sg0,
    const int* __restrict__ sg1, float* __restrict__ sg_lik, float* __restrict__ stats)
{
    int e = blockIdx.x * 256 + threadIdx.x;
    float x = 0.f;
    if (e < NES) {
        const float* a = means + (size_t)sg0[e] * EMBD;
        const float* b = means + (size_t)sg1[e] * EMBD;
        float s = 0.f;
#pragma unroll
        for (int j = 0; j < EMBD; ++j) s += a[j] * b[j];
        sg_lik[e] = s;
        x = s;
    }
    block_stats(x, &stats[0], &stats[1]);
}

__global__ __launch_bounds__(256) void sgw_kernel(
    const float* __restrict__ sg_lik, const float* __restrict__ stats,
    const float* __restrict__ gamma, const float* __restrict__ beta,
    float* __restrict__ out)
{
    int e = blockIdx.x * 256 + threadIdx.x;
    if (e >= NES) return;
    float m = stats[0] / (float)NES;
    float var = stats[1] / (float)NES - m * m;
    float y = (sg_lik[e] - m) * rsqrtf(var + 1e-5f) * gamma[0] + beta[0];
    out[e] = 1.f / (1.f + __expf(-y));
}

// bg_lik + per-dst histogram fused (same 800k-edge pass)
__global__ __launch_bounds__(256) void bg_lik_kernel(
    const float* __restrict__ emb, const float* __restrict__ means,
    const int* __restrict__ bg_src, const int* __restrict__ bg_dst,
    float* __restrict__ bg_lik, float* __restrict__ stats, int* __restrict__ cnt)
{
    int e = blockIdx.x * 256 + threadIdx.x;
    float x = 0.f;
    if (e < NEB) {
        int d = bg_dst[e];
        atomicAdd(&cnt[d], 1);
        const float* a = emb + (size_t)bg_src[e] * EMBD;
        const float* b = means + (size_t)d * EMBD;
        float s = 0.f;
#pragma unroll
        for (int j = 0; j < EMBD; ++j) s += a[j] * b[j];
        bg_lik[e] = s;
        x = s;
    }
    block_stats(x, &stats[2], &stats[3]);
}

__global__ __launch_bounds__(256) void bw_kernel(
    const float* __restrict__ bg_lik, const float* __restrict__ stats,
    const float* __restrict__ gamma, const float* __restrict__ beta,
    const int* __restrict__ bg_src, float* __restrict__ bw, float* __restrict__ denom)
{
    int e = blockIdx.x * 256 + threadIdx.x;
    if (e >= NEB) return;
    float m = stats[2] / (float)NEB;
    float var = stats[3] / (float)NEB - m * m;
    float y = (bg_lik[e] - m) * rsqrtf(var + 1e-5f) * gamma[0] + beta[0];
    float w = __expf(y);
    bw[e] = w;
    atomicAdd(&denom[bg_src[e]], w);
}

__global__ __launch_bounds__(256) void bw_norm_kernel(
    float* __restrict__ bw, const float* __restrict__ denom,
    const int* __restrict__ bg_src, float* __restrict__ out)
{
    int e = blockIdx.x * 256 + threadIdx.x;
    if (e >= NEB) return;
    float w = bw[e] / (1e-12f + denom[bg_src[e]]);
    bw[e] = w;
    out[e] = w;
}

// ---------------------------------------------------------------------------
__global__ __launch_bounds__(1024) void scan_kernel(
    const int* __restrict__ cnt, int* __restrict__ offs, int C)
{
    __shared__ int wsum[16];
    __shared__ int carry_s, ctot_s;
    const int tid = threadIdx.x;
    const int lane = tid & 63, w = tid >> 6;
    if (tid == 0) carry_s = 0;
    __syncthreads();
    for (int base = 0; base < C; base += 1024) {
        int i = base + tid;
        int v = (i < C) ? cnt[i] : 0;
        int x = v;
#pragma unroll
        for (int s = 1; s < 64; s <<= 1) {
            int y = __shfl_up(x, s, 64);
            if (lane >= s) x += y;
        }
        if (lane == 63) wsum[w] = x;
        __syncthreads();
        if (tid == 0) {
            int s = 0;
            for (int k = 0; k < 16; ++k) { int t = wsum[k]; wsum[k] = s; s += t; }
            ctot_s = s;
        }
        __syncthreads();
        int excl = carry_s + wsum[w] + (x - v);
        if (i < C) offs[i] = excl;
        __syncthreads();
        if (tid == 0) carry_s += ctot_s;
        __syncthreads();
    }
    if (tid == 0) offs[C] = carry_s;
}

__global__ void scatter_kernel(const int* __restrict__ bg_dst,
                               const int* __restrict__ offs,
                               int* __restrict__ fill, int* __restrict__ eids)
{
    int e = blockIdx.x * 256 + threadIdx.x;
    if (e >= NEB) return;
    int d = bg_dst[e];
    int p = atomicAdd(&fill[d], 1);
    eids[offs[d] + p] = e;
}

// ---------------------------------------------------------------------------
// supernodes[c][:] = sum_{e: bg_dst[e]==c} bw[e]*nmsg[bg_src[e]][:]  (nmsg bf16)
// x4 unrolled: 4 independent row-gathers in flight per block.
// ---------------------------------------------------------------------------
__global__ __launch_bounds__(128) void supernodes_kernel(
    const ushort_t* __restrict__ nmsg, const float* __restrict__ bw,
    const int* __restrict__ bg_src, const int* __restrict__ eids,
    const int* __restrict__ offs, float* __restrict__ sn)
{
    int c = blockIdx.x;
    int t = threadIdx.x;
    int beg = offs[c], end = offs[c + 1];
    float a0 = 0.f, a1 = 0.f, a2 = 0.f, a3 = 0.f;
    int p = beg;
    for (; p + 3 < end; p += 4) {
        int e0 = eids[p], e1 = eids[p + 1], e2 = eids[p + 2], e3 = eids[p + 3];
        int s0 = bg_src[e0], s1 = bg_src[e1], s2 = bg_src[e2], s3 = bg_src[e3];
        float w0 = bw[e0], w1 = bw[e1], w2 = bw[e2], w3 = bw[e3];
        ushort_t v0 = nmsg[(size_t)s0 * LATD + t];
        ushort_t v1 = nmsg[(size_t)s1 * LATD + t];
        ushort_t v2 = nmsg[(size_t)s2 * LATD + t];
        ushort_t v3 = nmsg[(size_t)s3 * LATD + t];
        a0 += w0 * bf2f(v0);
        a1 += w1 * bf2f(v1);
        a2 += w2 * bf2f(v2);
        a3 += w3 * bf2f(v3);
    }
    for (; p < end; ++p) {
        int e = eids[p];
        a0 += bw[e] * bf2f(nmsg[(size_t)bg_src[e] * LATD + t]);
    }
    sn[(size_t)c * LATD + t] = a0 + a1 + a2 + a3;
}

// ---------------------------------------------------------------------------
extern "C" void kernel_launch(void* const* d_in, const int* in_sizes, int n_in,
                              void* d_out, int out_size, void* d_ws, size_t ws_size,
                              hipStream_t stream)
{
    const float* emb_nodes = (const float*)d_in[0];
    const float* enc_nodes = (const float*)d_in[1];
    const float* Wc1 = (const float*)d_in[2];  const float* bc1 = (const float*)d_in[3];
    const float* Wc2 = (const float*)d_in[4];  const float* bc2 = (const float*)d_in[5];
    const float* Wc3 = (const float*)d_in[6];  const float* bc3 = (const float*)d_in[7];
    const float* Wn1 = (const float*)d_in[8];  const float* cn1 = (const float*)d_in[9];
    const float* Wn2 = (const float*)d_in[10]; const float* cn2 = (const float*)d_in[11];
    const float* We1 = (const float*)d_in[12]; const float* ce1 = (const float*)d_in[13];
    const float* We2 = (const float*)d_in[14]; const float* ce2 = (const float*)d_in[15];
    const float* sg_gamma = (const float*)d_in[16]; const float* sg_beta = (const float*)d_in[17];
    const float* bg_gamma = (const float*)d_in[18]; const float* bg_beta = (const float*)d_in[19];
    const int* clusters = (const int*)d_in[20];
    const int* sg0 = (const int*)d_in[21];
    const int* sg1 = sg0 + NES;
    const int* bg_src = (const int*)d_in[22];
    const int* bg_dst = (const int*)d_in[23];

    // output layout (flat, return order)
    float* out_emb = (float*)d_out;                       // NN*EMBD
    float* out_sn  = out_emb + (size_t)NN * EMBD;         // NC*LATD
    float* out_se  = out_sn + (size_t)NC * LATD;          // NES*LATD
    float* out_bw  = out_se + (size_t)NES * LATD;         // NEB
    float* out_sew = out_bw + (size_t)NEB;                // NES

    // ---------------- workspace layout (byte cursor, 64B-aligned) ----------
    uintptr_t cur = (uintptr_t)d_ws;
    uintptr_t wend = cur + ws_size;
    auto alloc = [&](size_t bytes) -> void* {
        cur = (cur + 63) & ~(uintptr_t)63;
        void* p = (void*)cur;
        cur += bytes;
        return p;
    };

    // zeroed region (contiguous)
    float* zbase = (float*)alloc(((size_t)NC * EMBD + NC + NN + 8 + NC + NC) * 4);
    float* csums = zbase;
    float* ccnt  = csums + (size_t)NC * EMBD;
    float* denom = ccnt + NC;
    float* stats = denom + NN;
    int*   cnt   = (int*)(stats + 8);
    int*   fill  = cnt + NC;
    size_t zero_bytes = ((size_t)NC * EMBD + NC + NN + 8 + NC + NC) * 4;

    float* means  = (float*)alloc((size_t)NC * EMBD * 4);
    float* sg_lik = (float*)alloc((size_t)NES * 4);
    float* bg_lik = (float*)alloc((size_t)NEB * 4);
    float* bwv    = (float*)alloc((size_t)NEB * 4);
    int*   offs   = (int*)alloc((size_t)(NC + 1) * 4);
    int*   eids   = (int*)alloc((size_t)NEB * 4);

    ushort_t* xemb   = (ushort_t*)alloc((size_t)NN * LATD * 2);
    ushort_t* xenc   = (ushort_t*)alloc((size_t)NN * LATD * 2);
    ushort_t* nmsgb  = (ushort_t*)alloc((size_t)NN * LATD * 2);
    ushort_t* sn_bf  = (ushort_t*)alloc((size_t)NC * LATD * 2);
    ushort_t* Wc1t = (ushort_t*)alloc((size_t)LATD * HIDD * 2);
    ushort_t* Wc2t = (ushort_t*)alloc((size_t)HIDD * HIDD * 2);
    ushort_t* Wn1t = (ushort_t*)alloc((size_t)LATD * HIDD * 2);
    ushort_t* Wn2t = (ushort_t*)alloc((size_t)HIDD * LATD * 2);
    ushort_t* We1t = (ushort_t*)alloc((size_t)2 * LATD * HIDD * 2);
    ushort_t* We2t = (ushort_t*)alloc((size_t)HIDD * LATD * 2);

    cur = (cur + 63) & ~(uintptr_t)63;
    size_t rem_bytes = (wend > cur) ? (size_t)(wend - cur) : 0;
    size_t chunk_sz = (rem_bytes / (2 * (size_t)HIDD * 2)) & ~(size_t)127;
    if (chunk_sz > 51200) chunk_sz = 51200;
    if (chunk_sz < 256) return;  // fail soft
    const int CH = (int)chunk_sz;
    ushort_t* bufA = (ushort_t*)cur;
    ushort_t* bufB = bufA + (size_t)CH * HIDD;

    hipMemsetAsync(zbase, 0, zero_bytes, stream);

    dim3 blk(256);

    // ---- prep: input/weight conversions ----
    conv_f2b_kernel<<<2048, blk, 0, stream>>>(emb_nodes, xemb, (long)NN * LATD);
    conv_f2b_kernel<<<2048, blk, 0, stream>>>(enc_nodes, xenc, (long)NN * LATD);
    transpose_conv_kernel<<<(LATD * HIDD + 255) / 256, blk, 0, stream>>>(Wc1, Wc1t, LATD, HIDD);
    transpose_conv_kernel<<<(HIDD * HIDD + 255) / 256, blk, 0, stream>>>(Wc2, Wc2t, HIDD, HIDD);
    transpose_conv_kernel<<<(LATD * HIDD + 255) / 256, blk, 0, stream>>>(Wn1, Wn1t, LATD, HIDD);
    transpose_conv_kernel<<<(HIDD * LATD + 255) / 256, blk, 0, stream>>>(Wn2, Wn2t, HIDD, LATD);
    transpose_conv_kernel<<<(2 * LATD * HIDD + 255) / 256, blk, 0, stream>>>(We1, We1t, 2 * LATD, HIDD);
    transpose_conv_kernel<<<(HIDD * LATD + 255) / 256, blk, 0, stream>>>(We2, We2t, HIDD, LATD);

    // ---- fused node chain, chunked: xemb->h1->h2->embeddings ----
    for (int m0 = 0; m0 < NN; m0 += CH) {
        int cm = (NN - m0 < CH) ? (NN - m0) : CH;
        gemm_mfma<ACT_TANH, false, true><<<dim3(HIDD / 128, (cm + 127) / 128), blk, 0, stream>>>(
            xemb + (size_t)m0 * LATD, Wc1t, bc1, bufA, cm, HIDD, LATD, nullptr, nullptr, nullptr);
        gemm_mfma<ACT_TANH, false, true><<<dim3(HIDD / 128, (cm + 127) / 128), blk, 0, stream>>>(
            bufA, Wc2t, bc2, bufB, cm, HIDD, HIDD, nullptr, nullptr, nullptr);
        emb_kernel<<<(cm + 255) / 256, blk, 0, stream>>>(
            bufB, Wc3, bc3, out_emb + (size_t)m0 * EMBD, cm);
    }

    // ---- cluster means ----
    cluster_accum<<<(NN * EMBD + 255) / 256, blk, 0, stream>>>(out_emb, clusters, csums, ccnt);
    means_kernel<<<(NC + 255) / 256, blk, 0, stream>>>(csums, ccnt, means);

    // ---- super edge weights ----
    sg_lik_kernel<<<(NES + 255) / 256, blk, 0, stream>>>(means, sg0, sg1, sg_lik, stats);
    sgw_kernel<<<(NES + 255) / 256, blk, 0, stream>>>(sg_lik, stats, sg_gamma, sg_beta, out_sew);

    // ---- bipartite edge weights (hist fused into bg_lik) ----
    bg_lik_kernel<<<(NEB + 255) / 256, blk, 0, stream>>>(out_emb, means, bg_src, bg_dst, bg_lik, stats, cnt);
    bw_kernel<<<(NEB + 255) / 256, blk, 0, stream>>>(bg_lik, stats, bg_gamma, bg_beta, bg_src, bwv, denom);
    bw_norm_kernel<<<(NEB + 255) / 256, blk, 0, stream>>>(bwv, denom, bg_src, out_bw);

    // ---- counting sort of edges by destination cluster ----
    scan_kernel<<<1, 1024, 0, stream>>>(cnt, offs, NC);
    scatter_kernel<<<(NEB + 255) / 256, blk, 0, stream>>>(bg_dst, offs, fill, eids);

    // ---- node messages, chunked: xenc->nm->nmsg(bf16, full) ----
    for (int m0 = 0; m0 < NN; m0 += CH) {
        int cm = (NN - m0 < CH) ? (NN - m0) : CH;
        gemm_mfma<ACT_RELU, false, true><<<dim3(HIDD / 128, (cm + 127) / 128), blk, 0, stream>>>(
            xenc + (size_t)m0 * LATD, Wn1t, cn1, bufA, cm, HIDD, LATD, nullptr, nullptr, nullptr);
        gemm_mfma<ACT_RELU, false, true><<<dim3(LATD / 128, (cm + 127) / 128), blk, 0, stream>>>(
            bufA, Wn2t, cn2, nmsgb + (size_t)m0 * LATD, cm, LATD, HIDD, nullptr, nullptr, nullptr);
    }

    // ---- supernodes (sorted edge lists, no atomics) ----
    supernodes_kernel<<<NC, 128, 0, stream>>>(nmsgb, bwv, bg_src, eids, offs, out_sn);
    conv_f2b_kernel<<<512, blk, 0, stream>>>(out_sn, sn_bf, (long)NC * LATD);

    // ---- superedges, chunked (bufA+bufB = one 2*CH-row region) ----
    const int CE = 2 * CH;
    for (int e0 = 0; e0 < NES; e0 += CE) {
        int ce = (NES - e0 < CE) ? (NES - e0) : CE;
        gemm_mfma<ACT_RELU, true, true><<<dim3(HIDD / 128, (ce + 127) / 128), blk, 0, stream>>>(
            nullptr, We1t, ce1, bufA, ce, HIDD, 2 * LATD, sg0 + e0, sg1 + e0, sn_bf);
        gemm_mfma<ACT_RELU, false, false><<<dim3(LATD / 128, (ce + 127) / 128), blk, 0, stream>>>(
            bufA, We2t, ce2, out_se + (size_t)e0 * LATD, ce, LATD, HIDD, nullptr, nullptr, nullptr);
    }
}